// Round 1
// baseline (1903.065 us; speedup 1.0000x reference)
//
#include <hip/hip_runtime.h>
#include <math.h>

// WaveletLayer: DWT(db2,symmetric) -> conv3+GELU (x2) -> IDWT -> out-projection
// B=8, S=2048, H=1024, fp32 throughout. Round-1 baseline: fp32 VALU tiled GEMMs.

namespace {

constexpr int Bc = 8;
constexpr int Sc = 2048;
constexpr int Hc = 1024;
constexpr int Mc = 1024;  // S/2 (truncated target)
constexpr int Tc = 1024;  // conv sequence length

constexpr double S3d = 1.7320508075688772935274463;
constexpr double DNd = 5.6568542494923801952067549;  // 4*sqrt(2)
constexpr float H0 = (float)((1.0 + S3d) / DNd);   //  0.4829629...
constexpr float H1 = (float)((3.0 + S3d) / DNd);   //  0.8365163...
constexpr float H2 = (float)((3.0 - S3d) / DNd);   //  0.2241438...
constexpr float H3 = (float)((1.0 - S3d) / DNd);   // -0.1294095...

// ---------------------------------------------------------------- transpose
// out[c][r] = in[r][c], R,C multiples of 32.
__global__ void transpose_k(const float* __restrict__ in, float* __restrict__ out,
                            int R, int C) {
  __shared__ float tile[32][33];
  const int c0 = blockIdx.x * 32;
  const int r0 = blockIdx.y * 32;
#pragma unroll
  for (int i = 0; i < 32; i += 8)
    tile[threadIdx.y + i][threadIdx.x] =
        in[(size_t)(r0 + threadIdx.y + i) * C + c0 + threadIdx.x];
  __syncthreads();
#pragma unroll
  for (int i = 0; i < 32; i += 8)
    out[(size_t)(c0 + threadIdx.y + i) * R + r0 + threadIdx.x] =
        tile[threadIdx.x][threadIdx.y + i];
}

// ---------------------------------------------------------------- DWT
// ca[m] = h0*x[2m-2] + h1*x[2m-1] + h2*x[2m] + h3*x[2m+1]
// cd[m] = h3*x[2m-2] - h2*x[2m-1] + h1*x[2m] - h0*x[2m+1]
// symmetric left reflection: index i<0 -> x[-i-1]. (right edge never hit, m<1024)
__global__ void dwt_kernel(const float* __restrict__ x, float* __restrict__ ca,
                           float* __restrict__ cd) {
  const int tid = blockIdx.x * 256 + threadIdx.x;  // over B*M*256 float4s
  const int h4 = (tid & 255) << 2;
  const int m = (tid >> 8) & (Mc - 1);
  const int b = tid >> 18;
  const float* xb = x + (size_t)b * Sc * Hc;
  float4 v[4];
#pragma unroll
  for (int t = 0; t < 4; ++t) {
    int i = 2 * m - 2 + t;
    if (i < 0) i = -i - 1;
    v[t] = *reinterpret_cast<const float4*>(&xb[(size_t)i * Hc + h4]);
  }
  float4 a, d;
  a.x = H0 * v[0].x + H1 * v[1].x + H2 * v[2].x + H3 * v[3].x;
  a.y = H0 * v[0].y + H1 * v[1].y + H2 * v[2].y + H3 * v[3].y;
  a.z = H0 * v[0].z + H1 * v[1].z + H2 * v[2].z + H3 * v[3].z;
  a.w = H0 * v[0].w + H1 * v[1].w + H2 * v[2].w + H3 * v[3].w;
  d.x = H3 * v[0].x - H2 * v[1].x + H1 * v[2].x - H0 * v[3].x;
  d.y = H3 * v[0].y - H2 * v[1].y + H1 * v[2].y - H0 * v[3].y;
  d.z = H3 * v[0].z - H2 * v[1].z + H1 * v[2].z - H0 * v[3].z;
  d.w = H3 * v[0].w - H2 * v[1].w + H1 * v[2].w - H0 * v[3].w;
  const size_t off = ((size_t)b * Mc + m) * Hc + h4;
  *reinterpret_cast<float4*>(&ca[off]) = a;
  *reinterpret_cast<float4*>(&cd[off]) = d;
}

// ---------------------------------------------------------------- conv3 + GELU
// y[b,t,o] = gelu( bias[o] + sum_{k,i} w[o,i,k] * c[b,t-1+k,i] ), zero-pad in t.
// wt is pre-transposed: wt[i*3+k][o].
// Tile: 128 t  x 128 o, BK=16 channels, 256 threads, 8x8 per thread (split 4+4).
__global__ __launch_bounds__(256) void conv_gelu_kernel(
    const float* __restrict__ Cin, const float* __restrict__ wt,
    const float* __restrict__ bias, float* __restrict__ Yout) {
  __shared__ float As[16][132];  // [BK][130 rows + pad] : input rows t0-1 .. t0+128
  __shared__ float Bs[48][128];  // [BK*3][o tile]
  const int tid = threadIdx.x;
  const int tx = tid & 15;
  const int ty = tid >> 4;
  const int b = blockIdx.z;
  const int t0 = blockIdx.y * 128;
  const int o0 = blockIdx.x * 128;
  const float* cb = Cin + (size_t)b * Tc * Hc;

  float acc[8][8];
#pragma unroll
  for (int i = 0; i < 8; ++i)
#pragma unroll
    for (int j = 0; j < 8; ++j) acc[i][j] = 0.f;

  for (int i0 = 0; i0 < Hc; i0 += 16) {
    __syncthreads();
    // stage A: 130 rows x 16 ch = 520 float4 (transposed store)
#pragma unroll
    for (int l = 0; l < 3; ++l) {
      const int fidx = tid + l * 256;
      if (fidx < 520) {
        const int rr = fidx >> 2;
        const int k4 = (fidx & 3) << 2;
        const int rg = t0 - 1 + rr;
        float4 v = make_float4(0.f, 0.f, 0.f, 0.f);
        if (rg >= 0 && rg < Tc)
          v = *reinterpret_cast<const float4*>(&cb[(size_t)rg * Hc + i0 + k4]);
        As[k4 + 0][rr] = v.x;
        As[k4 + 1][rr] = v.y;
        As[k4 + 2][rr] = v.z;
        As[k4 + 3][rr] = v.w;
      }
    }
    // stage B: 48 rows x 128 = 1536 float4
#pragma unroll
    for (int l = 0; l < 6; ++l) {
      const int fidx = tid + l * 256;
      const int rowk = fidx >> 5;  // 0..47  (== kk*3+k)
      const int c4 = (fidx & 31) << 2;
      *reinterpret_cast<float4*>(&Bs[rowk][c4]) =
          *reinterpret_cast<const float4*>(&wt[(size_t)(i0 * 3 + rowk) * Hc + o0 + c4]);
    }
    __syncthreads();

#pragma unroll
    for (int kk = 0; kk < 16; ++kk) {
      const float* ar = As[kk];
      float al[6], ah[6];
      {
        const float4 v0 = *reinterpret_cast<const float4*>(&ar[ty * 4]);
        const float2 v1 = *reinterpret_cast<const float2*>(&ar[ty * 4 + 4]);
        al[0] = v0.x; al[1] = v0.y; al[2] = v0.z; al[3] = v0.w; al[4] = v1.x; al[5] = v1.y;
        const float4 v2 = *reinterpret_cast<const float4*>(&ar[64 + ty * 4]);
        const float2 v3 = *reinterpret_cast<const float2*>(&ar[64 + ty * 4 + 4]);
        ah[0] = v2.x; ah[1] = v2.y; ah[2] = v2.z; ah[3] = v2.w; ah[4] = v3.x; ah[5] = v3.y;
      }
      float bl[3][4], bh[3][4];
#pragma unroll
      for (int k = 0; k < 3; ++k) {
        const float4 u0 = *reinterpret_cast<const float4*>(&Bs[kk * 3 + k][tx * 4]);
        const float4 u1 = *reinterpret_cast<const float4*>(&Bs[kk * 3 + k][64 + tx * 4]);
        bl[k][0] = u0.x; bl[k][1] = u0.y; bl[k][2] = u0.z; bl[k][3] = u0.w;
        bh[k][0] = u1.x; bh[k][1] = u1.y; bh[k][2] = u1.z; bh[k][3] = u1.w;
      }
#pragma unroll
      for (int k = 0; k < 3; ++k)
#pragma unroll
        for (int i = 0; i < 4; ++i)
#pragma unroll
          for (int j = 0; j < 4; ++j) {
            acc[i][j] = fmaf(al[i + k], bl[k][j], acc[i][j]);
            acc[i][j + 4] = fmaf(al[i + k], bh[k][j], acc[i][j + 4]);
            acc[i + 4][j] = fmaf(ah[i + k], bl[k][j], acc[i + 4][j]);
            acc[i + 4][j + 4] = fmaf(ah[i + k], bh[k][j], acc[i + 4][j + 4]);
          }
    }
  }

  const float4 bias_l = *reinterpret_cast<const float4*>(&bias[o0 + tx * 4]);
  const float4 bias_h = *reinterpret_cast<const float4*>(&bias[o0 + 64 + tx * 4]);
  const float blv[4] = {bias_l.x, bias_l.y, bias_l.z, bias_l.w};
  const float bhv[4] = {bias_h.x, bias_h.y, bias_h.z, bias_h.w};
  constexpr float RS2 = 0.70710678118654752440f;
#pragma unroll
  for (int i = 0; i < 8; ++i) {
    const int ti = t0 + ((i < 4) ? (ty * 4 + i) : (64 + ty * 4 + (i - 4)));
    float o8[8];
#pragma unroll
    for (int j = 0; j < 4; ++j) {
      const float yl = acc[i][j] + blv[j];
      o8[j] = 0.5f * yl * (1.f + erff(yl * RS2));
      const float yh = acc[i][j + 4] + bhv[j];
      o8[4 + j] = 0.5f * yh * (1.f + erff(yh * RS2));
    }
    float* orow = &Yout[((size_t)b * Tc + ti) * Hc + o0];
    *reinterpret_cast<float4*>(&orow[tx * 4]) = make_float4(o8[0], o8[1], o8[2], o8[3]);
    *reinterpret_cast<float4*>(&orow[64 + tx * 4]) = make_float4(o8[4], o8[5], o8[6], o8[7]);
  }
}

// ---------------------------------------------------------------- IDWT
// s even: r[s] = h0*pa[s/2+1] + h2*pa[s/2] + h3*pd[s/2+1] + h1*pd[s/2]
// s odd : r[s] = h1*pa[(s+1)/2] + h3*pa[(s-1)/2] - h2*pd[(s+1)/2] - h0*pd[(s-1)/2]
// s in [0,2046); rows 2046,2047 are zero padding.
__global__ void idwt_kernel(const float* __restrict__ pa, const float* __restrict__ pd,
                            float* __restrict__ recon) {
  const int tid = blockIdx.x * 256 + threadIdx.x;  // over B*S*256 float4s
  const int h4 = (tid & 255) << 2;
  const int s = (tid >> 8) & (Sc - 1);
  const int b = tid >> 19;
  const size_t ro = ((size_t)b * Sc + s) * Hc + h4;
  if (s >= Sc - 2) {
    *reinterpret_cast<float4*>(&recon[ro]) = make_float4(0.f, 0.f, 0.f, 0.f);
    return;
  }
  const float* pab = pa + (size_t)b * Mc * Hc;
  const float* pdb = pd + (size_t)b * Mc * Hc;
  float4 r;
  if ((s & 1) == 0) {
    const int m0 = s >> 1;
    const float4 aL = *reinterpret_cast<const float4*>(&pab[(size_t)m0 * Hc + h4]);
    const float4 aH = *reinterpret_cast<const float4*>(&pab[(size_t)(m0 + 1) * Hc + h4]);
    const float4 dL = *reinterpret_cast<const float4*>(&pdb[(size_t)m0 * Hc + h4]);
    const float4 dH = *reinterpret_cast<const float4*>(&pdb[(size_t)(m0 + 1) * Hc + h4]);
    r.x = H0 * aH.x + H2 * aL.x + H3 * dH.x + H1 * dL.x;
    r.y = H0 * aH.y + H2 * aL.y + H3 * dH.y + H1 * dL.y;
    r.z = H0 * aH.z + H2 * aL.z + H3 * dH.z + H1 * dL.z;
    r.w = H0 * aH.w + H2 * aL.w + H3 * dH.w + H1 * dL.w;
  } else {
    const int ml = (s - 1) >> 1;
    const int mh = ml + 1;
    const float4 aL = *reinterpret_cast<const float4*>(&pab[(size_t)ml * Hc + h4]);
    const float4 aH = *reinterpret_cast<const float4*>(&pab[(size_t)mh * Hc + h4]);
    const float4 dL = *reinterpret_cast<const float4*>(&pdb[(size_t)ml * Hc + h4]);
    const float4 dH = *reinterpret_cast<const float4*>(&pdb[(size_t)mh * Hc + h4]);
    r.x = H1 * aH.x + H3 * aL.x - H2 * dH.x - H0 * dL.x;
    r.y = H1 * aH.y + H3 * aL.y - H2 * dH.y - H0 * dL.y;
    r.z = H1 * aH.z + H3 * aL.z - H2 * dH.z - H0 * dL.z;
    r.w = H1 * aH.w + H3 * aL.w - H2 * dH.w - H0 * dL.w;
  }
  *reinterpret_cast<float4*>(&recon[ro]) = r;
}

// ---------------------------------------------------------------- out GEMM
// out[r][c] = sum_h A[r][h] * Bw[h][c] + bias[c]   (Bw = w_out transposed)
// 128x128 tile, BK=16, 256 threads, 8x8 per thread (split 4+4).
__global__ __launch_bounds__(256) void gemm_out_kernel(
    const float* __restrict__ A, const float* __restrict__ Bw,
    const float* __restrict__ bias, float* __restrict__ out) {
  __shared__ float As[16][128];
  __shared__ float Bs[16][128];
  const int tid = threadIdx.x;
  const int tx = tid & 15;
  const int ty = tid >> 4;
  const int row0 = blockIdx.y * 128;
  const int col0 = blockIdx.x * 128;

  float acc[8][8];
#pragma unroll
  for (int i = 0; i < 8; ++i)
#pragma unroll
    for (int j = 0; j < 8; ++j) acc[i][j] = 0.f;

  for (int k0 = 0; k0 < Hc; k0 += 16) {
    __syncthreads();
#pragma unroll
    for (int l = 0; l < 2; ++l) {
      const int fidx = tid + l * 256;  // 0..511
      const int r = fidx >> 2;
      const int k4 = (fidx & 3) << 2;
      const float4 v =
          *reinterpret_cast<const float4*>(&A[(size_t)(row0 + r) * Hc + k0 + k4]);
      As[k4 + 0][r] = v.x;
      As[k4 + 1][r] = v.y;
      As[k4 + 2][r] = v.z;
      As[k4 + 3][r] = v.w;
    }
#pragma unroll
    for (int l = 0; l < 2; ++l) {
      const int fidx = tid + l * 256;
      const int kk = fidx >> 5;
      const int c4 = (fidx & 31) << 2;
      *reinterpret_cast<float4*>(&Bs[kk][c4]) =
          *reinterpret_cast<const float4*>(&Bw[(size_t)(k0 + kk) * Hc + col0 + c4]);
    }
    __syncthreads();
#pragma unroll
    for (int kk = 0; kk < 16; ++kk) {
      const float4 a0 = *reinterpret_cast<const float4*>(&As[kk][ty * 4]);
      const float4 a1 = *reinterpret_cast<const float4*>(&As[kk][64 + ty * 4]);
      const float4 b0 = *reinterpret_cast<const float4*>(&Bs[kk][tx * 4]);
      const float4 b1 = *reinterpret_cast<const float4*>(&Bs[kk][64 + tx * 4]);
      const float a[8] = {a0.x, a0.y, a0.z, a0.w, a1.x, a1.y, a1.z, a1.w};
      const float bb[8] = {b0.x, b0.y, b0.z, b0.w, b1.x, b1.y, b1.z, b1.w};
#pragma unroll
      for (int i = 0; i < 8; ++i)
#pragma unroll
        for (int j = 0; j < 8; ++j) acc[i][j] = fmaf(a[i], bb[j], acc[i][j]);
    }
  }

  const float4 bias_l = *reinterpret_cast<const float4*>(&bias[col0 + tx * 4]);
  const float4 bias_h = *reinterpret_cast<const float4*>(&bias[col0 + 64 + tx * 4]);
#pragma unroll
  for (int i = 0; i < 8; ++i) {
    const int r = row0 + ((i < 4) ? (ty * 4 + i) : (64 + ty * 4 + (i - 4)));
    float* orow = &out[(size_t)r * Hc + col0];
    *reinterpret_cast<float4*>(&orow[tx * 4]) =
        make_float4(acc[i][0] + bias_l.x, acc[i][1] + bias_l.y, acc[i][2] + bias_l.z,
                    acc[i][3] + bias_l.w);
    *reinterpret_cast<float4*>(&orow[64 + tx * 4]) =
        make_float4(acc[i][4] + bias_h.x, acc[i][5] + bias_h.y, acc[i][6] + bias_h.z,
                    acc[i][7] + bias_h.w);
  }
}

}  // namespace

extern "C" void kernel_launch(void* const* d_in, const int* in_sizes, int n_in,
                              void* d_out, int out_size, void* d_ws, size_t ws_size,
                              hipStream_t stream) {
  const float* x = (const float*)d_in[0];         // [8,2048,1024]
  const float* w_approx = (const float*)d_in[1];  // [1024,1024,3]
  const float* b_approx = (const float*)d_in[2];  // [1024]
  const float* w_detail = (const float*)d_in[3];
  const float* b_detail = (const float*)d_in[4];
  const float* w_out = (const float*)d_in[5];  // [1024,1024]
  const float* b_out = (const float*)d_in[6];
  float* out = (float*)d_out;

  float* ws = (float*)d_ws;
  float* ca = ws;                    // 8M floats
  float* cd = ca + 8388608;          // 8M
  float* pa = cd + 8388608;          // 8M
  float* pd = pa + 8388608;          // 8M
  float* recon = pd + 8388608;       // 16M
  float* wtA = recon + 16777216;     // 3M  : [3072][1024]
  float* wtD = wtA + 3145728;        // 3M
  float* wtO = wtD + 3145728;        // 1M  : [1024][1024]

  const dim3 tb(32, 8);
  transpose_k<<<dim3(3072 / 32, 1024 / 32), tb, 0, stream>>>(w_approx, wtA, 1024, 3072);
  transpose_k<<<dim3(3072 / 32, 1024 / 32), tb, 0, stream>>>(w_detail, wtD, 1024, 3072);
  transpose_k<<<dim3(1024 / 32, 1024 / 32), tb, 0, stream>>>(w_out, wtO, 1024, 1024);

  dwt_kernel<<<8192, 256, 0, stream>>>(x, ca, cd);

  const dim3 cg(8, 8, 8);  // (o tiles, t tiles, batch)
  conv_gelu_kernel<<<cg, 256, 0, stream>>>(ca, wtA, b_approx, pa);
  conv_gelu_kernel<<<cg, 256, 0, stream>>>(cd, wtD, b_detail, pd);

  idwt_kernel<<<16384, 256, 0, stream>>>(pa, pd, recon);

  gemm_out_kernel<<<dim3(8, 128), 256, 0, stream>>>(recon, wtO, b_out, out);
}

// Round 4
// 617.121 us; speedup vs baseline: 3.0838x; 3.0838x over previous
//
#include <hip/hip_runtime.h>
#include <hip/hip_bf16.h>
#include <math.h>

// WaveletLayer: DWT(db2) -> conv3+GELU (x2) -> IDWT -> out-projection.
// Round 4 (= Round 2 kernel; bench infra timed out twice): all GEMM work on
// bf16 MFMA (16x16x32) with bf16x3 split compensation (hi*hi + hi*lo + lo*hi,
// fp32 accum) => fp32-grade accuracy at matrix-pipe speed.

namespace {

constexpr int Hc = 1024;
constexpr int Sc = 2048;
constexpr int Mcv = 1024;   // conv seq len (S/2)
constexpr int AROWS = 1026; // conv A buffer rows per batch (1 guard each side)

constexpr double S3d = 1.7320508075688772935274463;
constexpr double DNd = 5.6568542494923801952067549;  // 4*sqrt(2)
constexpr float W0 = (float)((1.0 + S3d) / DNd);
constexpr float W1 = (float)((3.0 + S3d) / DNd);
constexpr float W2 = (float)((3.0 - S3d) / DNd);
constexpr float W3 = (float)((1.0 - S3d) / DNd);

typedef short bf16x8 __attribute__((ext_vector_type(8)));  // 8 bf16 (4 VGPRs)
typedef float f32x4 __attribute__((ext_vector_type(4)));   // MFMA acc

typedef __attribute__((address_space(1))) const unsigned char ga_u8;
typedef __attribute__((address_space(3))) unsigned char la_u8;

__device__ __forceinline__ void gload16(const void* g, void* l) {
  // async global->LDS, 16B per lane; LDS dest = wave-uniform base + lane*16
  __builtin_amdgcn_global_load_lds((ga_u8*)g, (la_u8*)l, 16, 0, 0);
}

__device__ __forceinline__ void split1(float v, unsigned short& h, unsigned short& l) {
  __hip_bfloat16 hb = __float2bfloat16(v);
  float r = v - __bfloat162float(hb);
  __hip_bfloat16 lb = __float2bfloat16(r);
  h = *reinterpret_cast<unsigned short*>(&hb);
  l = *reinterpret_cast<unsigned short*>(&lb);
}

__device__ __forceinline__ void split4(const float4 v, ushort4& h, ushort4& l) {
  split1(v.x, h.x, l.x);
  split1(v.y, h.y, l.y);
  split1(v.z, h.z, l.z);
  split1(v.w, h.w, l.w);
}

// ---------------------------------------------------------------- DWT (+split)
// ca[m] = W0*x[2m-2] + W1*x[2m-1] + W2*x[2m] + W3*x[2m+1]   (symmetric left pad)
// cd[m] = W3*x[2m-2] - W2*x[2m-1] + W1*x[2m] - W0*x[2m+1]
// Writes bf16 hi/lo planes with guard rows (row 0 and row 1025 per batch zeroed).
__global__ void dwt_kernel(const float* __restrict__ x,
                           unsigned short* __restrict__ caH, unsigned short* __restrict__ caL,
                           unsigned short* __restrict__ cdH, unsigned short* __restrict__ cdL) {
  const int tid = blockIdx.x * 256 + threadIdx.x;
  const int h4 = (tid & 255) << 2;
  const int m = (tid >> 8) & (Mcv - 1);
  const int b = tid >> 18;
  const float* xb = x + (size_t)b * Sc * Hc;
  float4 v[4];
#pragma unroll
  for (int t = 0; t < 4; ++t) {
    int i = 2 * m - 2 + t;
    if (i < 0) i = -i - 1;
    v[t] = *reinterpret_cast<const float4*>(&xb[(size_t)i * Hc + h4]);
  }
  float4 a, d;
  a.x = W0 * v[0].x + W1 * v[1].x + W2 * v[2].x + W3 * v[3].x;
  a.y = W0 * v[0].y + W1 * v[1].y + W2 * v[2].y + W3 * v[3].y;
  a.z = W0 * v[0].z + W1 * v[1].z + W2 * v[2].z + W3 * v[3].z;
  a.w = W0 * v[0].w + W1 * v[1].w + W2 * v[2].w + W3 * v[3].w;
  d.x = W3 * v[0].x - W2 * v[1].x + W1 * v[2].x - W0 * v[3].x;
  d.y = W3 * v[0].y - W2 * v[1].y + W1 * v[2].y - W0 * v[3].y;
  d.z = W3 * v[0].z - W2 * v[1].z + W1 * v[2].z - W0 * v[3].z;
  d.w = W3 * v[0].w - W2 * v[1].w + W1 * v[2].w - W0 * v[3].w;

  const size_t row = (size_t)b * AROWS + 1 + m;
  ushort4 hh, ll;
  split4(a, hh, ll);
  *reinterpret_cast<ushort4*>(&caH[row * Hc + h4]) = hh;
  *reinterpret_cast<ushort4*>(&caL[row * Hc + h4]) = ll;
  split4(d, hh, ll);
  *reinterpret_cast<ushort4*>(&cdH[row * Hc + h4]) = hh;
  *reinterpret_cast<ushort4*>(&cdL[row * Hc + h4]) = ll;

  if (m == 0) {  // zero guard rows for this (b, h4)
    const ushort4 z4 = {0, 0, 0, 0};
    const size_t g0 = (size_t)b * AROWS * Hc + h4;
    const size_t g1 = ((size_t)b * AROWS + (AROWS - 1)) * Hc + h4;
    *reinterpret_cast<ushort4*>(&caH[g0]) = z4;
    *reinterpret_cast<ushort4*>(&caL[g0]) = z4;
    *reinterpret_cast<ushort4*>(&cdH[g0]) = z4;
    *reinterpret_cast<ushort4*>(&cdL[g0]) = z4;
    *reinterpret_cast<ushort4*>(&caH[g1]) = z4;
    *reinterpret_cast<ushort4*>(&caL[g1]) = z4;
    *reinterpret_cast<ushort4*>(&cdH[g1]) = z4;
    *reinterpret_cast<ushort4*>(&cdL[g1]) = z4;
  }
}

// ---------------------------------------------------------------- weight prep
// w[o][i][k] fp32 -> per-tap planes wt[k][o][i] bf16 hi/lo (B-operand layout:
// row = output col o, contiguous k-dim = input channel i).
__global__ void prep_conv_w(const float* __restrict__ wA, const float* __restrict__ wD,
                            unsigned short* __restrict__ aH, unsigned short* __restrict__ aL,
                            unsigned short* __restrict__ dH, unsigned short* __restrict__ dL) {
  const int idx = blockIdx.x * 256 + threadIdx.x;  // 2*1024*256
  const int i4 = idx & 255;
  const int o = (idx >> 8) & 1023;
  const int c = idx >> 18;
  const float* w = c ? wD : wA;
  unsigned short* oh = c ? dH : aH;
  unsigned short* ol = c ? dL : aL;
  const float* src = w + (size_t)o * 3072 + i4 * 12;
  const float4 f0 = *reinterpret_cast<const float4*>(src);
  const float4 f1 = *reinterpret_cast<const float4*>(src + 4);
  const float4 f2 = *reinterpret_cast<const float4*>(src + 8);
  const float e[12] = {f0.x, f0.y, f0.z, f0.w, f1.x, f1.y, f1.z, f1.w,
                       f2.x, f2.y, f2.z, f2.w};
#pragma unroll
  for (int k = 0; k < 3; ++k) {
    float4 v = make_float4(e[k], e[3 + k], e[6 + k], e[9 + k]);
    ushort4 hh, ll;
    split4(v, hh, ll);
    const size_t off = (size_t)k * 1048576 + (size_t)o * 1024 + i4 * 4;
    *reinterpret_cast<ushort4*>(&oh[off]) = hh;
    *reinterpret_cast<ushort4*>(&ol[off]) = ll;
  }
}

__global__ void prep_wout(const float* __restrict__ w,
                          unsigned short* __restrict__ oh, unsigned short* __restrict__ ol) {
  const int idx = blockIdx.x * 256 + threadIdx.x;  // 1024*256
  const size_t off = (size_t)(idx >> 8) * 1024 + (idx & 255) * 4;
  ushort4 hh, ll;
  split4(*reinterpret_cast<const float4*>(&w[off]), hh, ll);
  *reinterpret_cast<ushort4*>(&oh[off]) = hh;
  *reinterpret_cast<ushort4*>(&ol[off]) = ll;
}

// ---------------------------------------------------------------- MFMA GEMM
// Y[row][col] = [gelu](bias[col] + sum_tap sum_k A[arow0+tap+row][k] * B[tap][col][k])
// A: bf16 hi/lo planes [.. rows ..][1024]; B: [TAPS][1024 cols][1024 k] hi/lo.
// bf16x3: hh + hl + lh. 128x128 tile, BK=32, 4 waves (2x2), 4x4 16x16 frags/wave.
// LDS XOR-swizzle (slot ^= (row>>1)&3) applied on ds_read; staged via
// pre-swizzled per-lane GLOBAL source with linear global_load_lds dest (T21).
template <int TAPS, bool GELU>
__global__ __launch_bounds__(256, 2) void mm_kernel(
    const unsigned short* __restrict__ Ahi, const unsigned short* __restrict__ Alo,
    const unsigned short* __restrict__ Bhi, const unsigned short* __restrict__ Blo,
    const float* __restrict__ bias, float* __restrict__ Yout,
    int a_batch_rows, int y_batch_rows) {
  __shared__ __align__(16) unsigned short lds[16384];  // 32 KB
  unsigned short* AsH = lds;            // [128][32]
  unsigned short* AsL = lds + 4096;
  unsigned short* BsH = lds + 8192;
  unsigned short* BsL = lds + 12288;

  const int tid = threadIdx.x;
  const int lane = tid & 63;
  const int wave = tid >> 6;
  const int wm = wave >> 1, wn = wave & 1;
  const int o0 = blockIdx.x * 128;
  const int t0 = blockIdx.y * 128;
  const int z = blockIdx.z;
  const int arow0 = z * a_batch_rows + t0;

  f32x4 acc[4][4];
#pragma unroll
  for (int m = 0; m < 4; ++m)
#pragma unroll
    for (int n = 0; n < 4; ++n) acc[m][n] = (f32x4){0.f, 0.f, 0.f, 0.f};

  // staging geometry: seg j covers rows 16j..16j+15 of a [128][32]-ushort tile
  const int q = lane >> 2;                               // row within seg
  const int srcslot = (lane & 3) ^ ((lane >> 3) & 3);    // pre-swizzled source slot
  const int l15 = lane & 15;
  const int g = lane >> 4;

#pragma unroll 1
  for (int tap = 0; tap < TAPS; ++tap) {
    const unsigned short* bHp = Bhi + (size_t)tap * 1048576;
    const unsigned short* bLp = Blo + (size_t)tap * 1048576;
    const int abase = arow0 + tap;
#pragma unroll 1
    for (int c0 = 0; c0 < 1024; c0 += 32) {
      __syncthreads();  // all waves done reading previous tile
#pragma unroll
      for (int jj = 0; jj < 2; ++jj) {
        const int seg = wave * 2 + jj;
        const int r = seg * 16 + q;
        const size_t asrc = (size_t)(abase + r) * 1024 + c0 + srcslot * 8;
        const size_t bsrc = (size_t)(o0 + r) * 1024 + c0 + srcslot * 8;
        unsigned short* ldst = lds + seg * 512;
        gload16(Ahi + asrc, ldst);            // AsH
        gload16(Alo + asrc, ldst + 4096);     // AsL
        gload16(bHp + bsrc, ldst + 8192);     // BsH
        gload16(bLp + bsrc, ldst + 12288);    // BsL
      }
      __syncthreads();  // vmcnt drained by barrier semantics

      bf16x8 aH[4], aL[4], bH[4], bL[4];
#pragma unroll
      for (int m = 0; m < 4; ++m) {
        const int r = wm * 64 + m * 16 + l15;
        const int off = r * 32 + (g ^ ((r >> 1) & 3)) * 8;
        aH[m] = *reinterpret_cast<const bf16x8*>(AsH + off);
        aL[m] = *reinterpret_cast<const bf16x8*>(AsL + off);
      }
#pragma unroll
      for (int n = 0; n < 4; ++n) {
        const int r = wn * 64 + n * 16 + l15;
        const int off = r * 32 + (g ^ ((r >> 1) & 3)) * 8;
        bH[n] = *reinterpret_cast<const bf16x8*>(BsH + off);
        bL[n] = *reinterpret_cast<const bf16x8*>(BsL + off);
      }
#pragma unroll
      for (int m = 0; m < 4; ++m)
#pragma unroll
        for (int n = 0; n < 4; ++n) {
          acc[m][n] = __builtin_amdgcn_mfma_f32_16x16x32_bf16(aH[m], bH[n], acc[m][n], 0, 0, 0);
          acc[m][n] = __builtin_amdgcn_mfma_f32_16x16x32_bf16(aH[m], bL[n], acc[m][n], 0, 0, 0);
          acc[m][n] = __builtin_amdgcn_mfma_f32_16x16x32_bf16(aL[m], bH[n], acc[m][n], 0, 0, 0);
        }
    }
  }

  // epilogue: C/D frag (col = lane&15, row = (lane>>4)*4 + reg)  [m89]
  const int yrow0 = z * y_batch_rows + t0 + wm * 64;
  constexpr float RS2 = 0.70710678118654752440f;
#pragma unroll
  for (int n = 0; n < 4; ++n) {
    const int col = o0 + wn * 64 + n * 16 + l15;
    const float bv = bias[col];
#pragma unroll
    for (int m = 0; m < 4; ++m) {
      const int rbase = yrow0 + m * 16 + g * 4;
#pragma unroll
      for (int r = 0; r < 4; ++r) {
        float v = acc[m][n][r] + bv;
        if (GELU) v = 0.5f * v * (1.f + erff(v * RS2));
        Yout[(size_t)(rbase + r) * 1024 + col] = v;
      }
    }
  }
}

// ---------------------------------------------------------------- IDWT (+split)
__global__ void idwt_kernel(const float* __restrict__ pa, const float* __restrict__ pd,
                            unsigned short* __restrict__ rH, unsigned short* __restrict__ rL) {
  const int tid = blockIdx.x * 256 + threadIdx.x;
  const int h4 = (tid & 255) << 2;
  const int s = (tid >> 8) & (Sc - 1);
  const int b = tid >> 19;
  const size_t ro = ((size_t)b * Sc + s) * Hc + h4;
  if (s >= Sc - 2) {
    const ushort4 z4 = {0, 0, 0, 0};
    *reinterpret_cast<ushort4*>(&rH[ro]) = z4;
    *reinterpret_cast<ushort4*>(&rL[ro]) = z4;
    return;
  }
  const float* pab = pa + (size_t)b * Mcv * Hc;
  const float* pdb = pd + (size_t)b * Mcv * Hc;
  float4 r;
  if ((s & 1) == 0) {
    const int m0 = s >> 1;
    const float4 aL = *reinterpret_cast<const float4*>(&pab[(size_t)m0 * Hc + h4]);
    const float4 aH = *reinterpret_cast<const float4*>(&pab[(size_t)(m0 + 1) * Hc + h4]);
    const float4 dL = *reinterpret_cast<const float4*>(&pdb[(size_t)m0 * Hc + h4]);
    const float4 dH = *reinterpret_cast<const float4*>(&pdb[(size_t)(m0 + 1) * Hc + h4]);
    r.x = W0 * aH.x + W2 * aL.x + W3 * dH.x + W1 * dL.x;
    r.y = W0 * aH.y + W2 * aL.y + W3 * dH.y + W1 * dL.y;
    r.z = W0 * aH.z + W2 * aL.z + W3 * dH.z + W1 * dL.z;
    r.w = W0 * aH.w + W2 * aL.w + W3 * dH.w + W1 * dL.w;
  } else {
    const int ml = (s - 1) >> 1;
    const int mh = ml + 1;
    const float4 aL = *reinterpret_cast<const float4*>(&pab[(size_t)ml * Hc + h4]);
    const float4 aH = *reinterpret_cast<const float4*>(&pab[(size_t)mh * Hc + h4]);
    const float4 dL = *reinterpret_cast<const float4*>(&pdb[(size_t)ml * Hc + h4]);
    const float4 dH = *reinterpret_cast<const float4*>(&pdb[(size_t)mh * Hc + h4]);
    r.x = W1 * aH.x + W3 * aL.x - W2 * dH.x - W0 * dL.x;
    r.y = W1 * aH.y + W3 * aL.y - W2 * dH.y - W0 * dL.y;
    r.z = W1 * aH.z + W3 * aL.z - W2 * dH.z - W0 * dL.z;
    r.w = W1 * aH.w + W3 * aL.w - W2 * dH.w - W0 * dL.w;
  }
  ushort4 hh, ll;
  split4(r, hh, ll);
  *reinterpret_cast<ushort4*>(&rH[ro]) = hh;
  *reinterpret_cast<ushort4*>(&rL[ro]) = ll;
}

}  // namespace

extern "C" void kernel_launch(void* const* d_in, const int* in_sizes, int n_in,
                              void* d_out, int out_size, void* d_ws, size_t ws_size,
                              hipStream_t stream) {
  const float* x = (const float*)d_in[0];
  const float* w_approx = (const float*)d_in[1];
  const float* b_approx = (const float*)d_in[2];
  const float* w_detail = (const float*)d_in[3];
  const float* b_detail = (const float*)d_in[4];
  const float* w_out = (const float*)d_in[5];
  const float* b_out = (const float*)d_in[6];
  float* out = (float*)d_out;

  char* ws = (char*)d_ws;
  // A-split buffers (with guard rows): 8*1026*1024 ushorts = 16,809,984 B each
  unsigned short* caH = (unsigned short*)(ws);
  unsigned short* caL = (unsigned short*)(ws + 16809984);
  unsigned short* cdH = (unsigned short*)(ws + 33619968);
  unsigned short* cdL = (unsigned short*)(ws + 50429952);
  float* pa = (float*)(ws + 67239936);           // 33,554,432 B
  float* pd = (float*)(ws + 100794368);          // 33,554,432 B
  unsigned short* wtAh = (unsigned short*)(ws + 134348800);  // 6,291,456 B each
  unsigned short* wtAl = (unsigned short*)(ws + 140640256);
  unsigned short* wtDh = (unsigned short*)(ws + 146931712);
  unsigned short* wtDl = (unsigned short*)(ws + 153223168);
  unsigned short* woH = (unsigned short*)(ws + 159514624);   // 2,097,152 B each
  unsigned short* woL = (unsigned short*)(ws + 161611776);
  // recon hi/lo alias the (dead-by-then) ca/cd region: 33,554,432 B each
  unsigned short* rcH = (unsigned short*)(ws);
  unsigned short* rcL = (unsigned short*)(ws + 33619968);

  prep_conv_w<<<2048, 256, 0, stream>>>(w_approx, w_detail, wtAh, wtAl, wtDh, wtDl);
  prep_wout<<<1024, 256, 0, stream>>>(w_out, woH, woL);
  dwt_kernel<<<8192, 256, 0, stream>>>(x, caH, caL, cdH, cdL);

  mm_kernel<3, true><<<dim3(8, 8, 8), 256, 0, stream>>>(caH, caL, wtAh, wtAl,
                                                        b_approx, pa, AROWS, Mcv);
  mm_kernel<3, true><<<dim3(8, 8, 8), 256, 0, stream>>>(cdH, cdL, wtDh, wtDl,
                                                        b_detail, pd, AROWS, Mcv);

  idwt_kernel<<<16384, 256, 0, stream>>>(pa, pd, rcH, rcL);

  mm_kernel<1, false><<<dim3(8, 128, 1), 256, 0, stream>>>(rcH, rcL, woH, woL,
                                                           b_out, out, 0, 0);
}

// Round 5
// 560.401 us; speedup vs baseline: 3.3959x; 1.1012x over previous
//
#include <hip/hip_runtime.h>
#include <hip/hip_bf16.h>
#include <math.h>

// WaveletLayer: DWT(db2) -> conv3+GELU (x2) -> IDWT -> out-projection.
// Round 5: bf16x3 MFMA with (1) tap-shared A tile (130-row LDS tile serves all
// 3 taps -> A traffic / 3, 144 MFMA per barrier phase), (2) both convs merged
// into one 1024-block dispatch, (3) XCD-aware swizzle so blocks sharing an
// A-panel land on one XCD's L2.

namespace {

constexpr int Hc = 1024;
constexpr int Sc = 2048;
constexpr int Mcv = 1024;   // conv seq len (S/2)
constexpr int AROWS = 1026; // conv A rows per batch-plane (1 guard each side)

constexpr double S3d = 1.7320508075688772935274463;
constexpr double DNd = 5.6568542494923801952067549;  // 4*sqrt(2)
constexpr float W0 = (float)((1.0 + S3d) / DNd);
constexpr float W1 = (float)((3.0 + S3d) / DNd);
constexpr float W2 = (float)((3.0 - S3d) / DNd);
constexpr float W3 = (float)((1.0 - S3d) / DNd);

typedef short bf16x8 __attribute__((ext_vector_type(8)));
typedef float f32x4 __attribute__((ext_vector_type(4)));

typedef __attribute__((address_space(1))) const unsigned char ga_u8;
typedef __attribute__((address_space(3))) unsigned char la_u8;

__device__ __forceinline__ void gload16(const void* g, void* l) {
  __builtin_amdgcn_global_load_lds((ga_u8*)g, (la_u8*)l, 16, 0, 0);
}

__device__ __forceinline__ void split1(float v, unsigned short& h, unsigned short& l) {
  __hip_bfloat16 hb = __float2bfloat16(v);
  float r = v - __bfloat162float(hb);
  __hip_bfloat16 lb = __float2bfloat16(r);
  h = *reinterpret_cast<unsigned short*>(&hb);
  l = *reinterpret_cast<unsigned short*>(&lb);
}

__device__ __forceinline__ void split4(const float4 v, ushort4& h, ushort4& l) {
  split1(v.x, h.x, l.x);
  split1(v.y, h.y, l.y);
  split1(v.z, h.z, l.z);
  split1(v.w, h.w, l.w);
}

// ---------------------------------------------------------------- DWT (+split)
// Writes merged A buffer: batches 0..7 = ca, 8..15 = cd (AROWS rows each, with
// zeroed guard rows 0 and 1025 per batch-plane). Planes AH (hi) / AL (lo).
__global__ void dwt_kernel(const float* __restrict__ x,
                           unsigned short* __restrict__ AH,
                           unsigned short* __restrict__ AL) {
  const int tid = blockIdx.x * 256 + threadIdx.x;
  const int h4 = (tid & 255) << 2;
  const int m = (tid >> 8) & (Mcv - 1);
  const int b = tid >> 18;
  const float* xb = x + (size_t)b * Sc * Hc;
  float4 v[4];
#pragma unroll
  for (int t = 0; t < 4; ++t) {
    int i = 2 * m - 2 + t;
    if (i < 0) i = -i - 1;
    v[t] = *reinterpret_cast<const float4*>(&xb[(size_t)i * Hc + h4]);
  }
  float4 a, d;
  a.x = W0 * v[0].x + W1 * v[1].x + W2 * v[2].x + W3 * v[3].x;
  a.y = W0 * v[0].y + W1 * v[1].y + W2 * v[2].y + W3 * v[3].y;
  a.z = W0 * v[0].z + W1 * v[1].z + W2 * v[2].z + W3 * v[3].z;
  a.w = W0 * v[0].w + W1 * v[1].w + W2 * v[2].w + W3 * v[3].w;
  d.x = W3 * v[0].x - W2 * v[1].x + W1 * v[2].x - W0 * v[3].x;
  d.y = W3 * v[0].y - W2 * v[1].y + W1 * v[2].y - W0 * v[3].y;
  d.z = W3 * v[0].z - W2 * v[1].z + W1 * v[2].z - W0 * v[3].z;
  d.w = W3 * v[0].w - W2 * v[1].w + W1 * v[2].w - W0 * v[3].w;

  const size_t rowA = (size_t)b * AROWS + 1 + m;          // ca -> batch b
  const size_t rowD = (size_t)(b + 8) * AROWS + 1 + m;    // cd -> batch b+8
  ushort4 hh, ll;
  split4(a, hh, ll);
  *reinterpret_cast<ushort4*>(&AH[rowA * Hc + h4]) = hh;
  *reinterpret_cast<ushort4*>(&AL[rowA * Hc + h4]) = ll;
  split4(d, hh, ll);
  *reinterpret_cast<ushort4*>(&AH[rowD * Hc + h4]) = hh;
  *reinterpret_cast<ushort4*>(&AL[rowD * Hc + h4]) = ll;

  if (m == 0) {  // zero the 4 guard rows this (b,h4) owns, both planes
    const ushort4 z4 = {0, 0, 0, 0};
    const size_t gr[4] = {(size_t)b * AROWS,       (size_t)b * AROWS + AROWS - 1,
                          (size_t)(b + 8) * AROWS, (size_t)(b + 8) * AROWS + AROWS - 1};
#pragma unroll
    for (int i = 0; i < 4; ++i) {
      *reinterpret_cast<ushort4*>(&AH[gr[i] * Hc + h4]) = z4;
      *reinterpret_cast<ushort4*>(&AL[gr[i] * Hc + h4]) = z4;
    }
  }
}

// ---------------------------------------------------------------- weight prep
__global__ void prep_conv_w(const float* __restrict__ wA, const float* __restrict__ wD,
                            unsigned short* __restrict__ aH, unsigned short* __restrict__ aL,
                            unsigned short* __restrict__ dH, unsigned short* __restrict__ dL) {
  const int idx = blockIdx.x * 256 + threadIdx.x;  // 2*1024*256
  const int i4 = idx & 255;
  const int o = (idx >> 8) & 1023;
  const int c = idx >> 18;
  const float* w = c ? wD : wA;
  unsigned short* oh = c ? dH : aH;
  unsigned short* ol = c ? dL : aL;
  const float* src = w + (size_t)o * 3072 + i4 * 12;
  const float4 f0 = *reinterpret_cast<const float4*>(src);
  const float4 f1 = *reinterpret_cast<const float4*>(src + 4);
  const float4 f2 = *reinterpret_cast<const float4*>(src + 8);
  const float e[12] = {f0.x, f0.y, f0.z, f0.w, f1.x, f1.y, f1.z, f1.w,
                       f2.x, f2.y, f2.z, f2.w};
#pragma unroll
  for (int k = 0; k < 3; ++k) {
    float4 v = make_float4(e[k], e[3 + k], e[6 + k], e[9 + k]);
    ushort4 hh, ll;
    split4(v, hh, ll);
    const size_t off = (size_t)k * 1048576 + (size_t)o * 1024 + i4 * 4;
    *reinterpret_cast<ushort4*>(&oh[off]) = hh;
    *reinterpret_cast<ushort4*>(&ol[off]) = ll;
  }
}

__global__ void prep_wout(const float* __restrict__ w,
                          unsigned short* __restrict__ oh, unsigned short* __restrict__ ol) {
  const int idx = blockIdx.x * 256 + threadIdx.x;  // 1024*256
  const size_t off = (size_t)(idx >> 8) * 1024 + (idx & 255) * 4;
  ushort4 hh, ll;
  split4(*reinterpret_cast<const float4*>(&w[off]), hh, ll);
  *reinterpret_cast<ushort4*>(&oh[off]) = hh;
  *reinterpret_cast<ushort4*>(&ol[off]) = ll;
}

// ---------------------------------------------------------------- conv MFMA
// One dispatch for both convs. z = 0..15 (0-7: ca->pa with A-weights, 8-15:
// cd->pd with D-weights). Tap-shared A tile: stage rows [arow0, arow0+129]
// once per k-step; tap reads at row r+tap. B: 6 tap-planes resident.
// 1D grid 1024, swizzled: t = id&7 (-> XCD), o = (id>>3)&7, z = id>>6.
__global__ __launch_bounds__(256, 2) void conv_mm_kernel(
    const unsigned short* __restrict__ AH, const unsigned short* __restrict__ AL,
    const unsigned short* __restrict__ BAh, const unsigned short* __restrict__ BAl,
    const unsigned short* __restrict__ BDh, const unsigned short* __restrict__ BDl,
    const float* __restrict__ biasA, const float* __restrict__ biasD,
    float* __restrict__ Yout) {
  // LDS (ushorts): AsH[130][32] @0, AsL @4160, Bs[tap*2+plane][128][32] @8320+tp*4096
  __shared__ __align__(16) unsigned short lds[32896];  // 65,792 B

  const int tid = threadIdx.x;
  const int lane = tid & 63;
  const int wave = tid >> 6;
  const int wm = wave >> 1, wn = wave & 1;

  const int id = blockIdx.x;
  const int t = id & 7;            // t-tile -> XCD
  const int o = (id >> 3) & 7;
  const int z = id >> 6;           // 0..15
  const int o0 = o * 128;
  const int t0 = t * 128;
  const int arow0 = z * AROWS + t0;  // tap-0 input row for output row t0

  const unsigned short* BH = (z < 8) ? BAh : BDh;
  const unsigned short* BL = (z < 8) ? BAl : BDl;
  const float* bias = (z < 8) ? biasA : biasD;

  f32x4 acc[4][4];
#pragma unroll
  for (int m = 0; m < 4; ++m)
#pragma unroll
    for (int n = 0; n < 4; ++n) acc[m][n] = (f32x4){0.f, 0.f, 0.f, 0.f};

  const int q = lane >> 2;
  const int srcslot = (lane & 3) ^ ((lane >> 3) & 3);  // pre-swizzled source slot
  const int l15 = lane & 15;
  const int g = lane >> 4;

  // staging roles: waves 0,1 stage A-hi; 2,3 A-lo (4 segs each + tail on 0,2);
  // every wave stages segs {2w,2w+1} of all 6 B tap-planes.
  const int aplane = wave >> 1;
  const int aseg0 = (wave & 1) * 4;
  const unsigned short* Asrc = aplane ? AL : AH;
  unsigned short* Asbase = lds + aplane * 4160;

#pragma unroll 1
  for (int c0 = 0; c0 < 1024; c0 += 32) {
    __syncthreads();
    // A: 8 segs x 16 rows per plane + 2 tail rows (128,129)
#pragma unroll
    for (int j = 0; j < 4; ++j) {
      const int seg = aseg0 + j;
      const int r = seg * 16 + q;
      gload16(Asrc + (size_t)(arow0 + r) * 1024 + c0 + srcslot * 8,
              Asbase + seg * 512);
    }
    if ((wave & 1) == 0 && lane < 8) {  // rows 128..129: key=0, slot=lane&3
      const int r = 128 + (lane >> 2);
      gload16(Asrc + (size_t)(arow0 + r) * 1024 + c0 + (lane & 3) * 8,
              Asbase + 4096);
    }
    // B: 6 tap-planes x 8 segs
#pragma unroll
    for (int tp = 0; tp < 6; ++tp) {
      const unsigned short* bp =
          ((tp & 1) ? BL : BH) + (size_t)(tp >> 1) * 1048576;
      unsigned short* bdst = lds + 8320 + tp * 4096;
#pragma unroll
      for (int j = 0; j < 2; ++j) {
        const int seg = wave * 2 + j;
        const int r = seg * 16 + q;
        gload16(bp + (size_t)(o0 + r) * 1024 + c0 + srcslot * 8, bdst + seg * 512);
      }
    }
    __syncthreads();

#pragma unroll
    for (int tap = 0; tap < 3; ++tap) {
      bf16x8 aH4[4], aL4[4], bH4[4], bL4[4];
#pragma unroll
      for (int m = 0; m < 4; ++m) {
        const int r = wm * 64 + m * 16 + l15 + tap;  // tap shift in rows
        const int off = r * 32 + (g ^ ((r >> 1) & 3)) * 8;
        aH4[m] = *reinterpret_cast<const bf16x8*>(lds + off);
        aL4[m] = *reinterpret_cast<const bf16x8*>(lds + 4160 + off);
      }
#pragma unroll
      for (int n = 0; n < 4; ++n) {
        const int r = wn * 64 + n * 16 + l15;
        const int off = r * 32 + (g ^ ((r >> 1) & 3)) * 8;
        bH4[n] = *reinterpret_cast<const bf16x8*>(lds + 8320 + (tap * 2) * 4096 + off);
        bL4[n] = *reinterpret_cast<const bf16x8*>(lds + 8320 + (tap * 2 + 1) * 4096 + off);
      }
#pragma unroll
      for (int m = 0; m < 4; ++m)
#pragma unroll
        for (int n = 0; n < 4; ++n) {
          acc[m][n] = __builtin_amdgcn_mfma_f32_16x16x32_bf16(aH4[m], bH4[n], acc[m][n], 0, 0, 0);
          acc[m][n] = __builtin_amdgcn_mfma_f32_16x16x32_bf16(aH4[m], bL4[n], acc[m][n], 0, 0, 0);
          acc[m][n] = __builtin_amdgcn_mfma_f32_16x16x32_bf16(aL4[m], bH4[n], acc[m][n], 0, 0, 0);
        }
    }
  }

  // epilogue: C/D frag col = lane&15, row = (lane>>4)*4 + reg  [m89]
  const int yrow0 = z * Mcv + t0 + wm * 64;
  constexpr float RS2 = 0.70710678118654752440f;
#pragma unroll
  for (int n = 0; n < 4; ++n) {
    const int col = o0 + wn * 64 + n * 16 + l15;
    const float bv = bias[col];
#pragma unroll
    for (int m = 0; m < 4; ++m) {
      const int rbase = yrow0 + m * 16 + g * 4;
#pragma unroll
      for (int r = 0; r < 4; ++r) {
        float v = acc[m][n][r] + bv;
        v = 0.5f * v * (1.f + erff(v * RS2));
        Yout[(size_t)(rbase + r) * 1024 + col] = v;
      }
    }
  }
}

// ---------------------------------------------------------------- IDWT (+split)
// pout batches 0..7 = pa, 8..15 = pd.
__global__ void idwt_kernel(const float* __restrict__ pout,
                            unsigned short* __restrict__ rH, unsigned short* __restrict__ rL) {
  const int tid = blockIdx.x * 256 + threadIdx.x;
  const int h4 = (tid & 255) << 2;
  const int s = (tid >> 8) & (Sc - 1);
  const int b = tid >> 19;
  const size_t ro = ((size_t)b * Sc + s) * Hc + h4;
  if (s >= Sc - 2) {
    const ushort4 z4 = {0, 0, 0, 0};
    *reinterpret_cast<ushort4*>(&rH[ro]) = z4;
    *reinterpret_cast<ushort4*>(&rL[ro]) = z4;
    return;
  }
  const float* pab = pout + (size_t)b * Mcv * Hc;
  const float* pdb = pout + (size_t)(b + 8) * Mcv * Hc;
  float4 r;
  if ((s & 1) == 0) {
    const int m0 = s >> 1;
    const float4 aL = *reinterpret_cast<const float4*>(&pab[(size_t)m0 * Hc + h4]);
    const float4 aH = *reinterpret_cast<const float4*>(&pab[(size_t)(m0 + 1) * Hc + h4]);
    const float4 dL = *reinterpret_cast<const float4*>(&pdb[(size_t)m0 * Hc + h4]);
    const float4 dH = *reinterpret_cast<const float4*>(&pdb[(size_t)(m0 + 1) * Hc + h4]);
    r.x = W0 * aH.x + W2 * aL.x + W3 * dH.x + W1 * dL.x;
    r.y = W0 * aH.y + W2 * aL.y + W3 * dH.y + W1 * dL.y;
    r.z = W0 * aH.z + W2 * aL.z + W3 * dH.z + W1 * dL.z;
    r.w = W0 * aH.w + W2 * aL.w + W3 * dH.w + W1 * dL.w;
  } else {
    const int ml = (s - 1) >> 1;
    const int mh = ml + 1;
    const float4 aL = *reinterpret_cast<const float4*>(&pab[(size_t)ml * Hc + h4]);
    const float4 aH = *reinterpret_cast<const float4*>(&pab[(size_t)mh * Hc + h4]);
    const float4 dL = *reinterpret_cast<const float4*>(&pdb[(size_t)ml * Hc + h4]);
    const float4 dH = *reinterpret_cast<const float4*>(&pdb[(size_t)mh * Hc + h4]);
    r.x = W1 * aH.x + W3 * aL.x - W2 * dH.x - W0 * dL.x;
    r.y = W1 * aH.y + W3 * aL.y - W2 * dH.y - W0 * dL.y;
    r.z = W1 * aH.z + W3 * aL.z - W2 * dH.z - W0 * dL.z;
    r.w = W1 * aH.w + W3 * aL.w - W2 * dH.w - W0 * dL.w;
  }
  ushort4 hh, ll;
  split4(r, hh, ll);
  *reinterpret_cast<ushort4*>(&rH[ro]) = hh;
  *reinterpret_cast<ushort4*>(&rL[ro]) = ll;
}

// ---------------------------------------------------------------- out GEMM
// out[16384][1024] = rc . Wout^T + b. 1D grid 1024, swizzled so the 8
// col-blocks of one row-panel share an XCD: rowt = (id>>6)*8 + (id&7),
// col = (id>>3)&7.
__global__ __launch_bounds__(256, 2) void gemm_out_kernel(
    const unsigned short* __restrict__ Ahi, const unsigned short* __restrict__ Alo,
    const unsigned short* __restrict__ Bhi, const unsigned short* __restrict__ Blo,
    const float* __restrict__ bias, float* __restrict__ out) {
  __shared__ __align__(16) unsigned short lds[16384];  // 32 KB
  unsigned short* AsH = lds;
  unsigned short* AsL = lds + 4096;
  unsigned short* BsH = lds + 8192;
  unsigned short* BsL = lds + 12288;

  const int tid = threadIdx.x;
  const int lane = tid & 63;
  const int wave = tid >> 6;
  const int wm = wave >> 1, wn = wave & 1;

  const int id = blockIdx.x;
  const int rowt = (id >> 6) * 8 + (id & 7);  // 0..127 (-> XCD = id&7)
  const int col = (id >> 3) & 7;
  const int o0 = col * 128;
  const int t0 = rowt * 128;

  f32x4 acc[4][4];
#pragma unroll
  for (int m = 0; m < 4; ++m)
#pragma unroll
    for (int n = 0; n < 4; ++n) acc[m][n] = (f32x4){0.f, 0.f, 0.f, 0.f};

  const int q = lane >> 2;
  const int srcslot = (lane & 3) ^ ((lane >> 3) & 3);
  const int l15 = lane & 15;
  const int g = lane >> 4;

#pragma unroll 1
  for (int c0 = 0; c0 < 1024; c0 += 32) {
    __syncthreads();
#pragma unroll
    for (int jj = 0; jj < 2; ++jj) {
      const int seg = wave * 2 + jj;
      const int r = seg * 16 + q;
      const size_t asrc = (size_t)(t0 + r) * 1024 + c0 + srcslot * 8;
      const size_t bsrc = (size_t)(o0 + r) * 1024 + c0 + srcslot * 8;
      unsigned short* ldst = lds + seg * 512;
      gload16(Ahi + asrc, ldst);
      gload16(Alo + asrc, ldst + 4096);
      gload16(Bhi + bsrc, ldst + 8192);
      gload16(Blo + bsrc, ldst + 12288);
    }
    __syncthreads();

    bf16x8 aH[4], aL[4], bH[4], bL[4];
#pragma unroll
    for (int m = 0; m < 4; ++m) {
      const int r = wm * 64 + m * 16 + l15;
      const int off = r * 32 + (g ^ ((r >> 1) & 3)) * 8;
      aH[m] = *reinterpret_cast<const bf16x8*>(AsH + off);
      aL[m] = *reinterpret_cast<const bf16x8*>(AsL + off);
    }
#pragma unroll
    for (int n = 0; n < 4; ++n) {
      const int r = wn * 64 + n * 16 + l15;
      const int off = r * 32 + (g ^ ((r >> 1) & 3)) * 8;
      bH[n] = *reinterpret_cast<const bf16x8*>(BsH + off);
      bL[n] = *reinterpret_cast<const bf16x8*>(BsL + off);
    }
#pragma unroll
    for (int m = 0; m < 4; ++m)
#pragma unroll
      for (int n = 0; n < 4; ++n) {
        acc[m][n] = __builtin_amdgcn_mfma_f32_16x16x32_bf16(aH[m], bH[n], acc[m][n], 0, 0, 0);
        acc[m][n] = __builtin_amdgcn_mfma_f32_16x16x32_bf16(aH[m], bL[n], acc[m][n], 0, 0, 0);
        acc[m][n] = __builtin_amdgcn_mfma_f32_16x16x32_bf16(aL[m], bH[n], acc[m][n], 0, 0, 0);
      }
  }

  const int yrow0 = t0 + wm * 64;
#pragma unroll
  for (int n = 0; n < 4; ++n) {
    const int colg = o0 + wn * 64 + n * 16 + l15;
    const float bv = bias[colg];
#pragma unroll
    for (int m = 0; m < 4; ++m) {
      const int rbase = yrow0 + m * 16 + g * 4;
#pragma unroll
      for (int r = 0; r < 4; ++r)
        out[(size_t)(rbase + r) * 1024 + colg] = acc[m][n][r] + bv;
    }
  }
}

}  // namespace

extern "C" void kernel_launch(void* const* d_in, const int* in_sizes, int n_in,
                              void* d_out, int out_size, void* d_ws, size_t ws_size,
                              hipStream_t stream) {
  const float* x = (const float*)d_in[0];
  const float* w_approx = (const float*)d_in[1];
  const float* b_approx = (const float*)d_in[2];
  const float* w_detail = (const float*)d_in[3];
  const float* b_detail = (const float*)d_in[4];
  const float* w_out = (const float*)d_in[5];
  const float* b_out = (const float*)d_in[6];
  float* out = (float*)d_out;

  char* ws = (char*)d_ws;
  // merged A planes: 16 batches x 1026 rows x 1024 ushorts = 33,619,968 B each
  unsigned short* AH = (unsigned short*)(ws);
  unsigned short* AL = (unsigned short*)(ws + 33619968);
  float* pout = (float*)(ws + 67239936);                     // 16x1024x1024 f32 = 67,108,864 B
  unsigned short* wtAh = (unsigned short*)(ws + 134348800);  // 6,291,456 B each
  unsigned short* wtAl = (unsigned short*)(ws + 140640256);
  unsigned short* wtDh = (unsigned short*)(ws + 146931712);
  unsigned short* wtDl = (unsigned short*)(ws + 153223168);
  unsigned short* woH = (unsigned short*)(ws + 159514624);   // 2,097,152 B each
  unsigned short* woL = (unsigned short*)(ws + 161611776);
  // recon hi/lo alias the (dead-by-then) A region: 33,554,432 B each
  unsigned short* rcH = (unsigned short*)(ws);
  unsigned short* rcL = (unsigned short*)(ws + 33619968);

  prep_conv_w<<<2048, 256, 0, stream>>>(w_approx, w_detail, wtAh, wtAl, wtDh, wtDl);
  prep_wout<<<1024, 256, 0, stream>>>(w_out, woH, woL);
  dwt_kernel<<<8192, 256, 0, stream>>>(x, AH, AL);

  conv_mm_kernel<<<1024, 256, 0, stream>>>(AH, AL, wtAh, wtAl, wtDh, wtDl,
                                           b_approx, b_detail, pout);

  idwt_kernel<<<16384, 256, 0, stream>>>(pout, rcH, rcL);

  gemm_out_kernel<<<1024, 256, 0, stream>>>(rcH, rcL, woH, woL, b_out, out);
}

// Round 7
// 449.263 us; speedup vs baseline: 4.2360x; 1.2474x over previous
//
#include <hip/hip_runtime.h>
#include <hip/hip_bf16.h>
#include <math.h>

// WaveletLayer: DWT(db2) -> conv3+GELU (x2) -> IDWT -> out-projection.
// Round 7 (= Round 6 resubmit; bench infra timed out): bf16x2 split (data
// rounded to bf16, weights split hi/lo: a*(bH+bL)) => -33% MFMA work, half
// the data-plane traffic vs bf16x3. Tap-shared A tile + merged convs + XCD
// swizzle retained from Round 5.

namespace {

constexpr int Hc = 1024;
constexpr int Sc = 2048;
constexpr int Mcv = 1024;   // conv seq len (S/2)
constexpr int AROWS = 1026; // conv A rows per batch-plane (1 guard each side)

constexpr double S3d = 1.7320508075688772935274463;
constexpr double DNd = 5.6568542494923801952067549;  // 4*sqrt(2)
constexpr float W0 = (float)((1.0 + S3d) / DNd);
constexpr float W1 = (float)((3.0 + S3d) / DNd);
constexpr float W2 = (float)((3.0 - S3d) / DNd);
constexpr float W3 = (float)((1.0 - S3d) / DNd);

typedef short bf16x8 __attribute__((ext_vector_type(8)));
typedef float f32x4 __attribute__((ext_vector_type(4)));

typedef __attribute__((address_space(1))) const unsigned char ga_u8;
typedef __attribute__((address_space(3))) unsigned char la_u8;

__device__ __forceinline__ void gload16(const void* g, void* l) {
  __builtin_amdgcn_global_load_lds((ga_u8*)g, (la_u8*)l, 16, 0, 0);
}

__device__ __forceinline__ unsigned short rnd1(float v) {
  __hip_bfloat16 hb = __float2bfloat16(v);
  return *reinterpret_cast<unsigned short*>(&hb);
}

__device__ __forceinline__ ushort4 rnd4(const float4 v) {
  ushort4 h;
  h.x = rnd1(v.x); h.y = rnd1(v.y); h.z = rnd1(v.z); h.w = rnd1(v.w);
  return h;
}

__device__ __forceinline__ void split1(float v, unsigned short& h, unsigned short& l) {
  __hip_bfloat16 hb = __float2bfloat16(v);
  float r = v - __bfloat162float(hb);
  __hip_bfloat16 lb = __float2bfloat16(r);
  h = *reinterpret_cast<unsigned short*>(&hb);
  l = *reinterpret_cast<unsigned short*>(&lb);
}

__device__ __forceinline__ void split4(const float4 v, ushort4& h, ushort4& l) {
  split1(v.x, h.x, l.x);
  split1(v.y, h.y, l.y);
  split1(v.z, h.z, l.z);
  split1(v.w, h.w, l.w);
}

// ---------------------------------------------------------------- DWT
// Merged A buffer, single bf16 plane: batches 0..7 = ca, 8..15 = cd
// (AROWS rows each, guard rows 0 and 1025 zeroed per batch-plane).
__global__ void dwt_kernel(const float* __restrict__ x,
                           unsigned short* __restrict__ A) {
  const int tid = blockIdx.x * 256 + threadIdx.x;
  const int h4 = (tid & 255) << 2;
  const int m = (tid >> 8) & (Mcv - 1);
  const int b = tid >> 18;
  const float* xb = x + (size_t)b * Sc * Hc;
  float4 v[4];
#pragma unroll
  for (int t = 0; t < 4; ++t) {
    int i = 2 * m - 2 + t;
    if (i < 0) i = -i - 1;
    v[t] = *reinterpret_cast<const float4*>(&xb[(size_t)i * Hc + h4]);
  }
  float4 a, d;
  a.x = W0 * v[0].x + W1 * v[1].x + W2 * v[2].x + W3 * v[3].x;
  a.y = W0 * v[0].y + W1 * v[1].y + W2 * v[2].y + W3 * v[3].y;
  a.z = W0 * v[0].z + W1 * v[1].z + W2 * v[2].z + W3 * v[3].z;
  a.w = W0 * v[0].w + W1 * v[1].w + W2 * v[2].w + W3 * v[3].w;
  d.x = W3 * v[0].x - W2 * v[1].x + W1 * v[2].x - W0 * v[3].x;
  d.y = W3 * v[0].y - W2 * v[1].y + W1 * v[2].y - W0 * v[3].y;
  d.z = W3 * v[0].z - W2 * v[1].z + W1 * v[2].z - W0 * v[3].z;
  d.w = W3 * v[0].w - W2 * v[1].w + W1 * v[2].w - W0 * v[3].w;

  const size_t rowA = (size_t)b * AROWS + 1 + m;          // ca -> batch b
  const size_t rowD = (size_t)(b + 8) * AROWS + 1 + m;    // cd -> batch b+8
  *reinterpret_cast<ushort4*>(&A[rowA * Hc + h4]) = rnd4(a);
  *reinterpret_cast<ushort4*>(&A[rowD * Hc + h4]) = rnd4(d);

  if (m == 0) {  // zero the 4 guard rows this (b,h4) owns
    const ushort4 z4 = {0, 0, 0, 0};
    const size_t gr[4] = {(size_t)b * AROWS,       (size_t)b * AROWS + AROWS - 1,
                          (size_t)(b + 8) * AROWS, (size_t)(b + 8) * AROWS + AROWS - 1};
#pragma unroll
    for (int i = 0; i < 4; ++i)
      *reinterpret_cast<ushort4*>(&A[gr[i] * Hc + h4]) = z4;
  }
}

// ---------------------------------------------------------------- weight prep
// w[o][i][k] fp32 -> per-tap planes wt[k][o][i] bf16 hi/lo.
__global__ void prep_conv_w(const float* __restrict__ wA, const float* __restrict__ wD,
                            unsigned short* __restrict__ aH, unsigned short* __restrict__ aL,
                            unsigned short* __restrict__ dH, unsigned short* __restrict__ dL) {
  const int idx = blockIdx.x * 256 + threadIdx.x;  // 2*1024*256
  const int i4 = idx & 255;
  const int o = (idx >> 8) & 1023;
  const int c = idx >> 18;
  const float* w = c ? wD : wA;
  unsigned short* oh = c ? dH : aH;
  unsigned short* ol = c ? dL : aL;
  const float* src = w + (size_t)o * 3072 + i4 * 12;
  const float4 f0 = *reinterpret_cast<const float4*>(src);
  const float4 f1 = *reinterpret_cast<const float4*>(src + 4);
  const float4 f2 = *reinterpret_cast<const float4*>(src + 8);
  const float e[12] = {f0.x, f0.y, f0.z, f0.w, f1.x, f1.y, f1.z, f1.w,
                       f2.x, f2.y, f2.z, f2.w};
#pragma unroll
  for (int k = 0; k < 3; ++k) {
    float4 v = make_float4(e[k], e[3 + k], e[6 + k], e[9 + k]);
    ushort4 hh, ll;
    split4(v, hh, ll);
    const size_t off = (size_t)k * 1048576 + (size_t)o * 1024 + i4 * 4;
    *reinterpret_cast<ushort4*>(&oh[off]) = hh;
    *reinterpret_cast<ushort4*>(&ol[off]) = ll;
  }
}

__global__ void prep_wout(const float* __restrict__ w,
                          unsigned short* __restrict__ oh, unsigned short* __restrict__ ol) {
  const int idx = blockIdx.x * 256 + threadIdx.x;  // 1024*256
  const size_t off = (size_t)(idx >> 8) * 1024 + (idx & 255) * 4;
  ushort4 hh, ll;
  split4(*reinterpret_cast<const float4*>(&w[off]), hh, ll);
  *reinterpret_cast<ushort4*>(&oh[off]) = hh;
  *reinterpret_cast<ushort4*>(&ol[off]) = ll;
}

// ---------------------------------------------------------------- conv MFMA
// One dispatch for both convs. z = 0..15 (0-7: ca with A-weights, 8-15: cd
// with D-weights). Tap-shared A tile (single bf16 plane, 130 rows); B = 6
// resident tap-planes (3 taps x hi/lo). 2 MFMA per (m,n,tap): a*bH + a*bL.
// 1D grid 1024, swizzled: t = id&7 (-> XCD), o = (id>>3)&7, z = id>>6.
__global__ __launch_bounds__(256, 2) void conv_mm_kernel(
    const unsigned short* __restrict__ A,
    const unsigned short* __restrict__ BAh, const unsigned short* __restrict__ BAl,
    const unsigned short* __restrict__ BDh, const unsigned short* __restrict__ BDl,
    const float* __restrict__ biasA, const float* __restrict__ biasD,
    float* __restrict__ Yout) {
  // LDS (ushorts): As[130][32] @0 (4160), Bs[tap*2+plane][128][32] @4160+tp*4096
  __shared__ __align__(16) unsigned short lds[28736];  // 57,472 B

  const int tid = threadIdx.x;
  const int lane = tid & 63;
  const int wave = tid >> 6;
  const int wm = wave >> 1, wn = wave & 1;

  const int id = blockIdx.x;
  const int t = id & 7;            // t-tile -> XCD
  const int o = (id >> 3) & 7;
  const int z = id >> 6;           // 0..15
  const int o0 = o * 128;
  const int t0 = t * 128;
  const int arow0 = z * AROWS + t0;  // tap-0 input row for output row t0

  const unsigned short* BH = (z < 8) ? BAh : BDh;
  const unsigned short* BL = (z < 8) ? BAl : BDl;
  const float* bias = (z < 8) ? biasA : biasD;

  f32x4 acc[4][4];
#pragma unroll
  for (int m = 0; m < 4; ++m)
#pragma unroll
    for (int n = 0; n < 4; ++n) acc[m][n] = (f32x4){0.f, 0.f, 0.f, 0.f};

  const int q = lane >> 2;
  const int srcslot = (lane & 3) ^ ((lane >> 3) & 3);  // pre-swizzled source slot
  const int l15 = lane & 15;
  const int g = lane >> 4;

#pragma unroll 1
  for (int c0 = 0; c0 < 1024; c0 += 32) {
    __syncthreads();
    // A: 8 segs of 16 rows + 2 tail rows (128,129); wave w stages segs 2w,2w+1
#pragma unroll
    for (int j = 0; j < 2; ++j) {
      const int seg = wave * 2 + j;
      const int r = seg * 16 + q;
      gload16(A + (size_t)(arow0 + r) * 1024 + c0 + srcslot * 8, lds + seg * 512);
    }
    if (wave == 0 && lane < 8) {  // rows 128..129: swizzle key = 0
      const int r = 128 + (lane >> 2);
      gload16(A + (size_t)(arow0 + r) * 1024 + c0 + (lane & 3) * 8, lds + 4096);
    }
    // B: 6 tap-planes x 8 segs; wave w stages segs 2w,2w+1 of each plane
#pragma unroll
    for (int tp = 0; tp < 6; ++tp) {
      const unsigned short* bp =
          ((tp & 1) ? BL : BH) + (size_t)(tp >> 1) * 1048576;
      unsigned short* bdst = lds + 4160 + tp * 4096;
#pragma unroll
      for (int j = 0; j < 2; ++j) {
        const int seg = wave * 2 + j;
        const int r = seg * 16 + q;
        gload16(bp + (size_t)(o0 + r) * 1024 + c0 + srcslot * 8, bdst + seg * 512);
      }
    }
    __syncthreads();

#pragma unroll
    for (int tap = 0; tap < 3; ++tap) {
      bf16x8 a4[4], bH4[4], bL4[4];
#pragma unroll
      for (int m = 0; m < 4; ++m) {
        const int r = wm * 64 + m * 16 + l15 + tap;  // tap shift in rows
        const int off = r * 32 + (g ^ ((r >> 1) & 3)) * 8;
        a4[m] = *reinterpret_cast<const bf16x8*>(lds + off);
      }
#pragma unroll
      for (int n = 0; n < 4; ++n) {
        const int r = wn * 64 + n * 16 + l15;
        const int off = r * 32 + (g ^ ((r >> 1) & 3)) * 8;
        bH4[n] = *reinterpret_cast<const bf16x8*>(lds + 4160 + (tap * 2) * 4096 + off);
        bL4[n] = *reinterpret_cast<const bf16x8*>(lds + 4160 + (tap * 2 + 1) * 4096 + off);
      }
#pragma unroll
      for (int m = 0; m < 4; ++m)
#pragma unroll
        for (int n = 0; n < 4; ++n) {
          acc[m][n] = __builtin_amdgcn_mfma_f32_16x16x32_bf16(a4[m], bH4[n], acc[m][n], 0, 0, 0);
          acc[m][n] = __builtin_amdgcn_mfma_f32_16x16x32_bf16(a4[m], bL4[n], acc[m][n], 0, 0, 0);
        }
    }
  }

  // epilogue: C/D frag col = lane&15, row = (lane>>4)*4 + reg  [m89]
  const int yrow0 = z * Mcv + t0 + wm * 64;
  constexpr float RS2 = 0.70710678118654752440f;
#pragma unroll
  for (int n = 0; n < 4; ++n) {
    const int col = o0 + wn * 64 + n * 16 + l15;
    const float bv = bias[col];
#pragma unroll
    for (int m = 0; m < 4; ++m) {
      const int rbase = yrow0 + m * 16 + g * 4;
#pragma unroll
      for (int r = 0; r < 4; ++r) {
        float v = acc[m][n][r] + bv;
        v = 0.5f * v * (1.f + erff(v * RS2));
        Yout[(size_t)(rbase + r) * 1024 + col] = v;
      }
    }
  }
}

// ---------------------------------------------------------------- IDWT
// pout batches 0..7 = pa, 8..15 = pd. Output: single rounded bf16 plane.
__global__ void idwt_kernel(const float* __restrict__ pout,
                            unsigned short* __restrict__ rc) {
  const int tid = blockIdx.x * 256 + threadIdx.x;
  const int h4 = (tid & 255) << 2;
  const int s = (tid >> 8) & (Sc - 1);
  const int b = tid >> 19;
  const size_t ro = ((size_t)b * Sc + s) * Hc + h4;
  if (s >= Sc - 2) {
    const ushort4 z4 = {0, 0, 0, 0};
    *reinterpret_cast<ushort4*>(&rc[ro]) = z4;
    return;
  }
  const float* pab = pout + (size_t)b * Mcv * Hc;
  const float* pdb = pout + (size_t)(b + 8) * Mcv * Hc;
  float4 r;
  if ((s & 1) == 0) {
    const int m0 = s >> 1;
    const float4 aL = *reinterpret_cast<const float4*>(&pab[(size_t)m0 * Hc + h4]);
    const float4 aH = *reinterpret_cast<const float4*>(&pab[(size_t)(m0 + 1) * Hc + h4]);
    const float4 dL = *reinterpret_cast<const float4*>(&pdb[(size_t)m0 * Hc + h4]);
    const float4 dH = *reinterpret_cast<const float4*>(&pdb[(size_t)(m0 + 1) * Hc + h4]);
    r.x = W0 * aH.x + W2 * aL.x + W3 * dH.x + W1 * dL.x;
    r.y = W0 * aH.y + W2 * aL.y + W3 * dH.y + W1 * dL.y;
    r.z = W0 * aH.z + W2 * aL.z + W3 * dH.z + W1 * dL.z;
    r.w = W0 * aH.w + W2 * aL.w + W3 * dH.w + W1 * dL.w;
  } else {
    const int ml = (s - 1) >> 1;
    const int mh = ml + 1;
    const float4 aL = *reinterpret_cast<const float4*>(&pab[(size_t)ml * Hc + h4]);
    const float4 aH = *reinterpret_cast<const float4*>(&pab[(size_t)mh * Hc + h4]);
    const float4 dL = *reinterpret_cast<const float4*>(&pdb[(size_t)ml * Hc + h4]);
    const float4 dH = *reinterpret_cast<const float4*>(&pdb[(size_t)mh * Hc + h4]);
    r.x = W1 * aH.x + W3 * aL.x - W2 * dH.x - W0 * dL.x;
    r.y = W1 * aH.y + W3 * aL.y - W2 * dH.y - W0 * dL.y;
    r.z = W1 * aH.z + W3 * aL.z - W2 * dH.z - W0 * dL.z;
    r.w = W1 * aH.w + W3 * aL.w - W2 * dH.w - W0 * dL.w;
  }
  *reinterpret_cast<ushort4*>(&rc[ro]) = rnd4(r);
}

// ---------------------------------------------------------------- out GEMM
// out[16384][1024] = rc . Wout^T + b. A = single bf16 plane; B = hi/lo.
// 1D grid 1024, swizzled: rowt = (id>>6)*8 + (id&7), col = (id>>3)&7.
__global__ __launch_bounds__(256, 4) void gemm_out_kernel(
    const unsigned short* __restrict__ Arc,
    const unsigned short* __restrict__ Bhi, const unsigned short* __restrict__ Blo,
    const float* __restrict__ bias, float* __restrict__ out) {
  __shared__ __align__(16) unsigned short lds[12288];  // 24,576 B
  unsigned short* As = lds;           // [128][32]
  unsigned short* BsH = lds + 4096;
  unsigned short* BsL = lds + 8192;

  const int tid = threadIdx.x;
  const int lane = tid & 63;
  const int wave = tid >> 6;
  const int wm = wave >> 1, wn = wave & 1;

  const int id = blockIdx.x;
  const int rowt = (id >> 6) * 8 + (id & 7);  // 0..127 (-> XCD = id&7)
  const int col = (id >> 3) & 7;
  const int o0 = col * 128;
  const int t0 = rowt * 128;

  f32x4 acc[4][4];
#pragma unroll
  for (int m = 0; m < 4; ++m)
#pragma unroll
    for (int n = 0; n < 4; ++n) acc[m][n] = (f32x4){0.f, 0.f, 0.f, 0.f};

  const int q = lane >> 2;
  const int srcslot = (lane & 3) ^ ((lane >> 3) & 3);
  const int l15 = lane & 15;
  const int g = lane >> 4;

#pragma unroll 1
  for (int c0 = 0; c0 < 1024; c0 += 32) {
    __syncthreads();
#pragma unroll
    for (int jj = 0; jj < 2; ++jj) {
      const int seg = wave * 2 + jj;
      const int r = seg * 16 + q;
      const size_t asrc = (size_t)(t0 + r) * 1024 + c0 + srcslot * 8;
      const size_t bsrc = (size_t)(o0 + r) * 1024 + c0 + srcslot * 8;
      gload16(Arc + asrc, As + seg * 512);
      gload16(Bhi + bsrc, BsH + seg * 512);
      gload16(Blo + bsrc, BsL + seg * 512);
    }
    __syncthreads();

    bf16x8 a4[4], bH4[4], bL4[4];
#pragma unroll
    for (int m = 0; m < 4; ++m) {
      const int r = wm * 64 + m * 16 + l15;
      const int off = r * 32 + (g ^ ((r >> 1) & 3)) * 8;
      a4[m] = *reinterpret_cast<const bf16x8*>(As + off);
    }
#pragma unroll
    for (int n = 0; n < 4; ++n) {
      const int r = wn * 64 + n * 16 + l15;
      const int off = r * 32 + (g ^ ((r >> 1) & 3)) * 8;
      bH4[n] = *reinterpret_cast<const bf16x8*>(BsH + off);
      bL4[n] = *reinterpret_cast<const bf16x8*>(BsL + off);
    }
#pragma unroll
    for (int m = 0; m < 4; ++m)
#pragma unroll
      for (int n = 0; n < 4; ++n) {
        acc[m][n] = __builtin_amdgcn_mfma_f32_16x16x32_bf16(a4[m], bH4[n], acc[m][n], 0, 0, 0);
        acc[m][n] = __builtin_amdgcn_mfma_f32_16x16x32_bf16(a4[m], bL4[n], acc[m][n], 0, 0, 0);
      }
  }

  const int yrow0 = t0 + wm * 64;
#pragma unroll
  for (int n = 0; n < 4; ++n) {
    const int colg = o0 + wn * 64 + n * 16 + l15;
    const float bv = bias[colg];
#pragma unroll
    for (int m = 0; m < 4; ++m) {
      const int rbase = yrow0 + m * 16 + g * 4;
#pragma unroll
      for (int r = 0; r < 4; ++r)
        out[(size_t)(rbase + r) * 1024 + colg] = acc[m][n][r] + bv;
    }
  }
}

}  // namespace

extern "C" void kernel_launch(void* const* d_in, const int* in_sizes, int n_in,
                              void* d_out, int out_size, void* d_ws, size_t ws_size,
                              hipStream_t stream) {
  const float* x = (const float*)d_in[0];
  const float* w_approx = (const float*)d_in[1];
  const float* b_approx = (const float*)d_in[2];
  const float* w_detail = (const float*)d_in[3];
  const float* b_detail = (const float*)d_in[4];
  const float* w_out = (const float*)d_in[5];
  const float* b_out = (const float*)d_in[6];
  float* out = (float*)d_out;

  char* ws = (char*)d_ws;
  // merged A plane: 16 batches x 1026 rows x 1024 ushorts = 33,619,968 B
  unsigned short* A = (unsigned short*)(ws);
  float* pout = (float*)(ws + 33619968);                     // 16x1024x1024 f32 = 67,108,864 B
  unsigned short* rc = (unsigned short*)(ws + 100728832);    // 16384x1024 ushorts = 33,554,432 B
  unsigned short* wtAh = (unsigned short*)(ws + 134348800);  // 6,291,456 B each
  unsigned short* wtAl = (unsigned short*)(ws + 140640256);
  unsigned short* wtDh = (unsigned short*)(ws + 146931712);
  unsigned short* wtDl = (unsigned short*)(ws + 153223168);
  unsigned short* woH = (unsigned short*)(ws + 159514624);   // 2,097,152 B each
  unsigned short* woL = (unsigned short*)(ws + 161611776);

  prep_conv_w<<<2048, 256, 0, stream>>>(w_approx, w_detail, wtAh, wtAl, wtDh, wtDl);
  prep_wout<<<1024, 256, 0, stream>>>(w_out, woH, woL);
  dwt_kernel<<<8192, 256, 0, stream>>>(x, A);

  conv_mm_kernel<<<1024, 256, 0, stream>>>(A, wtAh, wtAl, wtDh, wtDl,
                                           b_approx, b_detail, pout);

  idwt_kernel<<<16384, 256, 0, stream>>>(pout, rc);

  gemm_out_kernel<<<1024, 256, 0, stream>>>(rc, woH, woL, b_out, out);
}

// Round 8
// 432.530 us; speedup vs baseline: 4.3998x; 1.0387x over previous
//
#include <hip/hip_runtime.h>
#include <hip/hip_bf16.h>
#include <math.h>

// WaveletLayer: DWT(db2) -> conv3+GELU (x2) -> IDWT -> out-projection.
// Round 8: BM=256 tiles (acc 8x4/wave, 128x64 out/wave) on conv and out-GEMM
// -> LDS-read:MFMA ratio 0.375->0.25, staging bytes/MFMA halved. bf16x2
// numerics, tap-shared A tile, merged convs, XCD swizzle retained.

namespace {

constexpr int Hc = 1024;
constexpr int Sc = 2048;
constexpr int Mcv = 1024;   // conv seq len (S/2)
constexpr int AROWS = 1026; // conv A rows per batch-plane (1 guard each side)

constexpr double S3d = 1.7320508075688772935274463;
constexpr double DNd = 5.6568542494923801952067549;  // 4*sqrt(2)
constexpr float W0 = (float)((1.0 + S3d) / DNd);
constexpr float W1 = (float)((3.0 + S3d) / DNd);
constexpr float W2 = (float)((3.0 - S3d) / DNd);
constexpr float W3 = (float)((1.0 - S3d) / DNd);

typedef short bf16x8 __attribute__((ext_vector_type(8)));
typedef float f32x4 __attribute__((ext_vector_type(4)));

typedef __attribute__((address_space(1))) const unsigned char ga_u8;
typedef __attribute__((address_space(3))) unsigned char la_u8;

__device__ __forceinline__ void gload16(const void* g, void* l) {
  __builtin_amdgcn_global_load_lds((ga_u8*)g, (la_u8*)l, 16, 0, 0);
}

__device__ __forceinline__ unsigned short rnd1(float v) {
  __hip_bfloat16 hb = __float2bfloat16(v);
  return *reinterpret_cast<unsigned short*>(&hb);
}

__device__ __forceinline__ ushort4 rnd4(const float4 v) {
  ushort4 h;
  h.x = rnd1(v.x); h.y = rnd1(v.y); h.z = rnd1(v.z); h.w = rnd1(v.w);
  return h;
}

__device__ __forceinline__ void split1(float v, unsigned short& h, unsigned short& l) {
  __hip_bfloat16 hb = __float2bfloat16(v);
  float r = v - __bfloat162float(hb);
  __hip_bfloat16 lb = __float2bfloat16(r);
  h = *reinterpret_cast<unsigned short*>(&hb);
  l = *reinterpret_cast<unsigned short*>(&lb);
}

__device__ __forceinline__ void split4(const float4 v, ushort4& h, ushort4& l) {
  split1(v.x, h.x, l.x);
  split1(v.y, h.y, l.y);
  split1(v.z, h.z, l.z);
  split1(v.w, h.w, l.w);
}

// ---------------------------------------------------------------- DWT
// Merged A buffer, single bf16 plane: batches 0..7 = ca, 8..15 = cd
// (AROWS rows each, guard rows 0 and 1025 zeroed per batch-plane).
__global__ void dwt_kernel(const float* __restrict__ x,
                           unsigned short* __restrict__ A) {
  const int tid = blockIdx.x * 256 + threadIdx.x;
  const int h4 = (tid & 255) << 2;
  const int m = (tid >> 8) & (Mcv - 1);
  const int b = tid >> 18;
  const float* xb = x + (size_t)b * Sc * Hc;
  float4 v[4];
#pragma unroll
  for (int t = 0; t < 4; ++t) {
    int i = 2 * m - 2 + t;
    if (i < 0) i = -i - 1;
    v[t] = *reinterpret_cast<const float4*>(&xb[(size_t)i * Hc + h4]);
  }
  float4 a, d;
  a.x = W0 * v[0].x + W1 * v[1].x + W2 * v[2].x + W3 * v[3].x;
  a.y = W0 * v[0].y + W1 * v[1].y + W2 * v[2].y + W3 * v[3].y;
  a.z = W0 * v[0].z + W1 * v[1].z + W2 * v[2].z + W3 * v[3].z;
  a.w = W0 * v[0].w + W1 * v[1].w + W2 * v[2].w + W3 * v[3].w;
  d.x = W3 * v[0].x - W2 * v[1].x + W1 * v[2].x - W0 * v[3].x;
  d.y = W3 * v[0].y - W2 * v[1].y + W1 * v[2].y - W0 * v[3].y;
  d.z = W3 * v[0].z - W2 * v[1].z + W1 * v[2].z - W0 * v[3].z;
  d.w = W3 * v[0].w - W2 * v[1].w + W1 * v[2].w - W0 * v[3].w;

  const size_t rowA = (size_t)b * AROWS + 1 + m;          // ca -> batch b
  const size_t rowD = (size_t)(b + 8) * AROWS + 1 + m;    // cd -> batch b+8
  *reinterpret_cast<ushort4*>(&A[rowA * Hc + h4]) = rnd4(a);
  *reinterpret_cast<ushort4*>(&A[rowD * Hc + h4]) = rnd4(d);

  if (m == 0) {  // zero the 4 guard rows this (b,h4) owns
    const ushort4 z4 = {0, 0, 0, 0};
    const size_t gr[4] = {(size_t)b * AROWS,       (size_t)b * AROWS + AROWS - 1,
                          (size_t)(b + 8) * AROWS, (size_t)(b + 8) * AROWS + AROWS - 1};
#pragma unroll
    for (int i = 0; i < 4; ++i)
      *reinterpret_cast<ushort4*>(&A[gr[i] * Hc + h4]) = z4;
  }
}

// ---------------------------------------------------------------- weight prep
// w[o][i][k] fp32 -> per-tap planes wt[k][o][i] bf16 hi/lo.
__global__ void prep_conv_w(const float* __restrict__ wA, const float* __restrict__ wD,
                            unsigned short* __restrict__ aH, unsigned short* __restrict__ aL,
                            unsigned short* __restrict__ dH, unsigned short* __restrict__ dL) {
  const int idx = blockIdx.x * 256 + threadIdx.x;  // 2*1024*256
  const int i4 = idx & 255;
  const int o = (idx >> 8) & 1023;
  const int c = idx >> 18;
  const float* w = c ? wD : wA;
  unsigned short* oh = c ? dH : aH;
  unsigned short* ol = c ? dL : aL;
  const float* src = w + (size_t)o * 3072 + i4 * 12;
  const float4 f0 = *reinterpret_cast<const float4*>(src);
  const float4 f1 = *reinterpret_cast<const float4*>(src + 4);
  const float4 f2 = *reinterpret_cast<const float4*>(src + 8);
  const float e[12] = {f0.x, f0.y, f0.z, f0.w, f1.x, f1.y, f1.z, f1.w,
                       f2.x, f2.y, f2.z, f2.w};
#pragma unroll
  for (int k = 0; k < 3; ++k) {
    float4 v = make_float4(e[k], e[3 + k], e[6 + k], e[9 + k]);
    ushort4 hh, ll;
    split4(v, hh, ll);
    const size_t off = (size_t)k * 1048576 + (size_t)o * 1024 + i4 * 4;
    *reinterpret_cast<ushort4*>(&oh[off]) = hh;
    *reinterpret_cast<ushort4*>(&ol[off]) = ll;
  }
}

__global__ void prep_wout(const float* __restrict__ w,
                          unsigned short* __restrict__ oh, unsigned short* __restrict__ ol) {
  const int idx = blockIdx.x * 256 + threadIdx.x;  // 1024*256
  const size_t off = (size_t)(idx >> 8) * 1024 + (idx & 255) * 4;
  ushort4 hh, ll;
  split4(*reinterpret_cast<const float4*>(&w[off]), hh, ll);
  *reinterpret_cast<ushort4*>(&oh[off]) = hh;
  *reinterpret_cast<ushort4*>(&ol[off]) = ll;
}

// ---------------------------------------------------------------- conv MFMA
// BM=256: block computes 256 t-rows x 128 o-cols. 4 waves (2x2), each wave
// 128x64 (acc 8x4 frags). Tap-shared A tile: 258 rows staged once per k-step.
// B: 6 resident tap-planes (3 taps x hi/lo). 2 MFMA per (m,n,tap).
// Grid 512: t = id&3 (-> XCD group), o = (id>>2)&7, z = id>>5.
__global__ __launch_bounds__(256, 2) void conv_mm_kernel(
    const unsigned short* __restrict__ A,
    const unsigned short* __restrict__ BAh, const unsigned short* __restrict__ BAl,
    const unsigned short* __restrict__ BDh, const unsigned short* __restrict__ BDl,
    const float* __restrict__ biasA, const float* __restrict__ biasD,
    float* __restrict__ Yout) {
  // LDS (ushorts): As[258][32] @0 (8256), Bs[tp][128][32] @8256+tp*4096
  __shared__ __align__(16) unsigned short lds[32832];  // 65,664 B

  const int tid = threadIdx.x;
  const int lane = tid & 63;
  const int wave = tid >> 6;
  const int wm = wave >> 1, wn = wave & 1;

  const int id = blockIdx.x;
  const int t = id & 3;
  const int o = (id >> 2) & 7;
  const int z = id >> 5;           // 0..15
  const int o0 = o * 128;
  const int t0 = t * 256;
  const int arow0 = z * AROWS + t0;  // tap-0 input row for output row t0

  const unsigned short* BH = (z < 8) ? BAh : BDh;
  const unsigned short* BL = (z < 8) ? BAl : BDl;
  const float* bias = (z < 8) ? biasA : biasD;

  f32x4 acc[8][4];
#pragma unroll
  for (int m = 0; m < 8; ++m)
#pragma unroll
    for (int n = 0; n < 4; ++n) acc[m][n] = (f32x4){0.f, 0.f, 0.f, 0.f};

  const int q = lane >> 2;
  const int srcslot = (lane & 3) ^ ((lane >> 3) & 3);  // pre-swizzled source slot
  const int l15 = lane & 15;
  const int g = lane >> 4;

#pragma unroll 1
  for (int c0 = 0; c0 < 1024; c0 += 32) {
    __syncthreads();
    // A: 16 segs of 16 rows (wave w: segs 4w..4w+3) + 2 tail rows (256,257)
#pragma unroll
    for (int j = 0; j < 4; ++j) {
      const int seg = wave * 4 + j;
      const int r = seg * 16 + q;
      gload16(A + (size_t)(arow0 + r) * 1024 + c0 + srcslot * 8, lds + seg * 512);
    }
    if (wave == 0 && lane < 8) {  // rows 256..257: swizzle key = 0
      const int r = 256 + (lane >> 2);
      gload16(A + (size_t)(arow0 + r) * 1024 + c0 + (lane & 3) * 8, lds + 8192);
    }
    // B: 6 tap-planes x 8 segs; wave w stages segs 2w,2w+1 of each plane
#pragma unroll
    for (int tp = 0; tp < 6; ++tp) {
      const unsigned short* bp =
          ((tp & 1) ? BL : BH) + (size_t)(tp >> 1) * 1048576;
      unsigned short* bdst = lds + 8256 + tp * 4096;
#pragma unroll
      for (int j = 0; j < 2; ++j) {
        const int seg = wave * 2 + j;
        const int r = seg * 16 + q;
        gload16(bp + (size_t)(o0 + r) * 1024 + c0 + srcslot * 8, bdst + seg * 512);
      }
    }
    __syncthreads();

#pragma unroll
    for (int tap = 0; tap < 3; ++tap) {
      bf16x8 a4[8], bH4[4], bL4[4];
#pragma unroll
      for (int m = 0; m < 8; ++m) {
        const int r = wm * 128 + m * 16 + l15 + tap;  // tap shift in rows
        const int off = r * 32 + (g ^ ((r >> 1) & 3)) * 8;
        a4[m] = *reinterpret_cast<const bf16x8*>(lds + off);
      }
#pragma unroll
      for (int n = 0; n < 4; ++n) {
        const int r = wn * 64 + n * 16 + l15;
        const int off = r * 32 + (g ^ ((r >> 1) & 3)) * 8;
        bH4[n] = *reinterpret_cast<const bf16x8*>(lds + 8256 + (tap * 2) * 4096 + off);
        bL4[n] = *reinterpret_cast<const bf16x8*>(lds + 8256 + (tap * 2 + 1) * 4096 + off);
      }
#pragma unroll
      for (int m = 0; m < 8; ++m)
#pragma unroll
        for (int n = 0; n < 4; ++n) {
          acc[m][n] = __builtin_amdgcn_mfma_f32_16x16x32_bf16(a4[m], bH4[n], acc[m][n], 0, 0, 0);
          acc[m][n] = __builtin_amdgcn_mfma_f32_16x16x32_bf16(a4[m], bL4[n], acc[m][n], 0, 0, 0);
        }
    }
  }

  // epilogue: C/D frag col = lane&15, row = (lane>>4)*4 + reg  [m89]
  const int yrow0 = z * Mcv + t0 + wm * 128;
  constexpr float RS2 = 0.70710678118654752440f;
#pragma unroll
  for (int n = 0; n < 4; ++n) {
    const int col = o0 + wn * 64 + n * 16 + l15;
    const float bv = bias[col];
#pragma unroll
    for (int m = 0; m < 8; ++m) {
      const int rbase = yrow0 + m * 16 + g * 4;
#pragma unroll
      for (int r = 0; r < 4; ++r) {
        float v = acc[m][n][r] + bv;
        v = 0.5f * v * (1.f + erff(v * RS2));
        Yout[(size_t)(rbase + r) * 1024 + col] = v;
      }
    }
  }
}

// ---------------------------------------------------------------- IDWT
// pout batches 0..7 = pa, 8..15 = pd. Output: single rounded bf16 plane.
__global__ void idwt_kernel(const float* __restrict__ pout,
                            unsigned short* __restrict__ rc) {
  const int tid = blockIdx.x * 256 + threadIdx.x;
  const int h4 = (tid & 255) << 2;
  const int s = (tid >> 8) & (Sc - 1);
  const int b = tid >> 19;
  const size_t ro = ((size_t)b * Sc + s) * Hc + h4;
  if (s >= Sc - 2) {
    const ushort4 z4 = {0, 0, 0, 0};
    *reinterpret_cast<ushort4*>(&rc[ro]) = z4;
    return;
  }
  const float* pab = pout + (size_t)b * Mcv * Hc;
  const float* pdb = pout + (size_t)(b + 8) * Mcv * Hc;
  float4 r;
  if ((s & 1) == 0) {
    const int m0 = s >> 1;
    const float4 aL = *reinterpret_cast<const float4*>(&pab[(size_t)m0 * Hc + h4]);
    const float4 aH = *reinterpret_cast<const float4*>(&pab[(size_t)(m0 + 1) * Hc + h4]);
    const float4 dL = *reinterpret_cast<const float4*>(&pdb[(size_t)m0 * Hc + h4]);
    const float4 dH = *reinterpret_cast<const float4*>(&pdb[(size_t)(m0 + 1) * Hc + h4]);
    r.x = W0 * aH.x + W2 * aL.x + W3 * dH.x + W1 * dL.x;
    r.y = W0 * aH.y + W2 * aL.y + W3 * dH.y + W1 * dL.y;
    r.z = W0 * aH.z + W2 * aL.z + W3 * dH.z + W1 * dL.z;
    r.w = W0 * aH.w + W2 * aL.w + W3 * dH.w + W1 * dL.w;
  } else {
    const int ml = (s - 1) >> 1;
    const int mh = ml + 1;
    const float4 aL = *reinterpret_cast<const float4*>(&pab[(size_t)ml * Hc + h4]);
    const float4 aH = *reinterpret_cast<const float4*>(&pab[(size_t)mh * Hc + h4]);
    const float4 dL = *reinterpret_cast<const float4*>(&pdb[(size_t)ml * Hc + h4]);
    const float4 dH = *reinterpret_cast<const float4*>(&pdb[(size_t)mh * Hc + h4]);
    r.x = W1 * aH.x + W3 * aL.x - W2 * dH.x - W0 * dL.x;
    r.y = W1 * aH.y + W3 * aL.y - W2 * dH.y - W0 * dL.y;
    r.z = W1 * aH.z + W3 * aL.z - W2 * dH.z - W0 * dL.z;
    r.w = W1 * aH.w + W3 * aL.w - W2 * dH.w - W0 * dL.w;
  }
  *reinterpret_cast<ushort4*>(&rc[ro]) = rnd4(r);
}

// ---------------------------------------------------------------- out GEMM
// BM=256: block computes 256 rows x 128 cols; 4 waves (2x2), acc 8x4/wave.
// Grid 512: rowt = (id>>6)*8 + (id&7) (0..63), col = (id>>3)&7; the 8
// col-blocks of one row-panel share id%8 -> same XCD.
__global__ __launch_bounds__(256, 2) void gemm_out_kernel(
    const unsigned short* __restrict__ Arc,
    const unsigned short* __restrict__ Bhi, const unsigned short* __restrict__ Blo,
    const float* __restrict__ bias, float* __restrict__ out) {
  __shared__ __align__(16) unsigned short lds[16384];  // 32 KB
  unsigned short* As = lds;            // [256][32]
  unsigned short* BsH = lds + 8192;    // [128][32]
  unsigned short* BsL = lds + 12288;

  const int tid = threadIdx.x;
  const int lane = tid & 63;
  const int wave = tid >> 6;
  const int wm = wave >> 1, wn = wave & 1;

  const int id = blockIdx.x;
  const int rowt = (id >> 6) * 8 + (id & 7);  // 0..63
  const int col = (id >> 3) & 7;
  const int o0 = col * 128;
  const int t0 = rowt * 256;

  f32x4 acc[8][4];
#pragma unroll
  for (int m = 0; m < 8; ++m)
#pragma unroll
    for (int n = 0; n < 4; ++n) acc[m][n] = (f32x4){0.f, 0.f, 0.f, 0.f};

  const int q = lane >> 2;
  const int srcslot = (lane & 3) ^ ((lane >> 3) & 3);
  const int l15 = lane & 15;
  const int g = lane >> 4;

#pragma unroll 1
  for (int c0 = 0; c0 < 1024; c0 += 32) {
    __syncthreads();
    // A: 16 segs (wave w: segs 4w..4w+3)
#pragma unroll
    for (int j = 0; j < 4; ++j) {
      const int seg = wave * 4 + j;
      const int r = seg * 16 + q;
      gload16(Arc + (size_t)(t0 + r) * 1024 + c0 + srcslot * 8, As + seg * 512);
    }
    // B: hi/lo x 8 segs (wave w: segs 2w,2w+1 per plane)
#pragma unroll
    for (int j = 0; j < 2; ++j) {
      const int seg = wave * 2 + j;
      const int r = seg * 16 + q;
      const size_t bsrc = (size_t)(o0 + r) * 1024 + c0 + srcslot * 8;
      gload16(Bhi + bsrc, BsH + seg * 512);
      gload16(Blo + bsrc, BsL + seg * 512);
    }
    __syncthreads();

    bf16x8 a4[8], bH4[4], bL4[4];
#pragma unroll
    for (int m = 0; m < 8; ++m) {
      const int r = wm * 128 + m * 16 + l15;
      const int off = r * 32 + (g ^ ((r >> 1) & 3)) * 8;
      a4[m] = *reinterpret_cast<const bf16x8*>(As + off);
    }
#pragma unroll
    for (int n = 0; n < 4; ++n) {
      const int r = wn * 64 + n * 16 + l15;
      const int off = r * 32 + (g ^ ((r >> 1) & 3)) * 8;
      bH4[n] = *reinterpret_cast<const bf16x8*>(BsH + off);
      bL4[n] = *reinterpret_cast<const bf16x8*>(BsL + off);
    }
#pragma unroll
    for (int m = 0; m < 8; ++m)
#pragma unroll
      for (int n = 0; n < 4; ++n) {
        acc[m][n] = __builtin_amdgcn_mfma_f32_16x16x32_bf16(a4[m], bH4[n], acc[m][n], 0, 0, 0);
        acc[m][n] = __builtin_amdgcn_mfma_f32_16x16x32_bf16(a4[m], bL4[n], acc[m][n], 0, 0, 0);
      }
  }

  const int yrow0 = t0 + wm * 128;
#pragma unroll
  for (int n = 0; n < 4; ++n) {
    const int colg = o0 + wn * 64 + n * 16 + l15;
    const float bv = bias[colg];
#pragma unroll
    for (int m = 0; m < 8; ++m) {
      const int rbase = yrow0 + m * 16 + g * 4;
#pragma unroll
      for (int r = 0; r < 4; ++r)
        out[(size_t)(rbase + r) * 1024 + colg] = acc[m][n][r] + bv;
    }
  }
}

}  // namespace

extern "C" void kernel_launch(void* const* d_in, const int* in_sizes, int n_in,
                              void* d_out, int out_size, void* d_ws, size_t ws_size,
                              hipStream_t stream) {
  const float* x = (const float*)d_in[0];
  const float* w_approx = (const float*)d_in[1];
  const float* b_approx = (const float*)d_in[2];
  const float* w_detail = (const float*)d_in[3];
  const float* b_detail = (const float*)d_in[4];
  const float* w_out = (const float*)d_in[5];
  const float* b_out = (const float*)d_in[6];
  float* out = (float*)d_out;

  char* ws = (char*)d_ws;
  // merged A plane: 16 batches x 1026 rows x 1024 ushorts = 33,619,968 B
  unsigned short* A = (unsigned short*)(ws);
  float* pout = (float*)(ws + 33619968);                     // 16x1024x1024 f32 = 67,108,864 B
  unsigned short* rc = (unsigned short*)(ws + 100728832);    // 16384x1024 ushorts = 33,554,432 B
  unsigned short* wtAh = (unsigned short*)(ws + 134348800);  // 6,291,456 B each
  unsigned short* wtAl = (unsigned short*)(ws + 140640256);
  unsigned short* wtDh = (unsigned short*)(ws + 146931712);
  unsigned short* wtDl = (unsigned short*)(ws + 153223168);
  unsigned short* woH = (unsigned short*)(ws + 159514624);   // 2,097,152 B each
  unsigned short* woL = (unsigned short*)(ws + 161611776);

  prep_conv_w<<<2048, 256, 0, stream>>>(w_approx, w_detail, wtAh, wtAl, wtDh, wtDl);
  prep_wout<<<1024, 256, 0, stream>>>(w_out, woH, woL);
  dwt_kernel<<<8192, 256, 0, stream>>>(x, A);

  conv_mm_kernel<<<512, 256, 0, stream>>>(A, wtAh, wtAl, wtDh, wtDl,
                                          b_approx, b_detail, pout);

  idwt_kernel<<<16384, 256, 0, stream>>>(pout, rc);

  gemm_out_kernel<<<512, 256, 0, stream>>>(rc, woH, woL, b_out, out);
}

// Round 10
// 408.891 us; speedup vs baseline: 4.6542x; 1.0578x over previous
//
#include <hip/hip_runtime.h>
#include <hip/hip_bf16.h>
#include <math.h>

// WaveletLayer: DWT(db2) -> conv3+GELU (x2) -> IDWT -> out-projection.
// Round 10 (= Round 9 resubmit; bench infra timed out): T3-minimum pipelined
// schedule (issue-early / drain-late, LDS double-buffer, one barrier per
// k-step) on conv (512 thr, 8 waves) and out-GEMM (256 thr, dbuf, 2
// blocks/CU). Paired dwt/idwt. bf16x2 numerics, tap-shared A, XCD swizzle.

namespace {

constexpr int Hc = 1024;
constexpr int Sc = 2048;
constexpr int Mcv = 1024;   // conv seq len (S/2)
constexpr int AROWS = 1026; // conv A rows per batch-plane (1 guard each side)

constexpr double S3d = 1.7320508075688772935274463;
constexpr double DNd = 5.6568542494923801952067549;  // 4*sqrt(2)
constexpr float W0 = (float)((1.0 + S3d) / DNd);
constexpr float W1 = (float)((3.0 + S3d) / DNd);
constexpr float W2 = (float)((3.0 - S3d) / DNd);
constexpr float W3 = (float)((1.0 - S3d) / DNd);

typedef short bf16x8 __attribute__((ext_vector_type(8)));
typedef float f32x4 __attribute__((ext_vector_type(4)));

typedef __attribute__((address_space(1))) const unsigned char ga_u8;
typedef __attribute__((address_space(3))) unsigned char la_u8;

__device__ __forceinline__ void gload16(const void* g, void* l) {
  __builtin_amdgcn_global_load_lds((ga_u8*)g, (la_u8*)l, 16, 0, 0);
}

__device__ __forceinline__ unsigned short rnd1(float v) {
  __hip_bfloat16 hb = __float2bfloat16(v);
  return *reinterpret_cast<unsigned short*>(&hb);
}

__device__ __forceinline__ ushort4 rnd4(const float4 v) {
  ushort4 h;
  h.x = rnd1(v.x); h.y = rnd1(v.y); h.z = rnd1(v.z); h.w = rnd1(v.w);
  return h;
}

__device__ __forceinline__ void split1(float v, unsigned short& h, unsigned short& l) {
  __hip_bfloat16 hb = __float2bfloat16(v);
  float r = v - __bfloat162float(hb);
  __hip_bfloat16 lb = __float2bfloat16(r);
  h = *reinterpret_cast<unsigned short*>(&hb);
  l = *reinterpret_cast<unsigned short*>(&lb);
}

__device__ __forceinline__ void split4(const float4 v, ushort4& h, ushort4& l) {
  split1(v.x, h.x, l.x);
  split1(v.y, h.y, l.y);
  split1(v.z, h.z, l.z);
  split1(v.w, h.w, l.w);
}

// ---------------------------------------------------------------- DWT
// Paired: each thread computes m and m+1 (6 x-rows instead of 8).
// Merged A buffer, single bf16 plane: batches 0..7 = ca, 8..15 = cd.
__global__ void dwt_kernel(const float* __restrict__ x,
                           unsigned short* __restrict__ A) {
  const int tid = blockIdx.x * 256 + threadIdx.x;  // 2^20 threads
  const int h4 = (tid & 255) << 2;
  const int mp = (tid >> 8) & 511;
  const int b = tid >> 17;
  const int m = mp * 2;
  const float* xb = x + (size_t)b * Sc * Hc;
  float4 v[6];
#pragma unroll
  for (int t = 0; t < 6; ++t) {
    int i = 2 * m - 2 + t;
    if (i < 0) i = -i - 1;  // symmetric left reflection
    v[t] = *reinterpret_cast<const float4*>(&xb[(size_t)i * Hc + h4]);
  }
  float4 a0, d0, a1, d1;
#define DWT_AD(ao, dd, u0, u1, u2, u3)                      \
  ao.x = W0*u0.x + W1*u1.x + W2*u2.x + W3*u3.x;             \
  ao.y = W0*u0.y + W1*u1.y + W2*u2.y + W3*u3.y;             \
  ao.z = W0*u0.z + W1*u1.z + W2*u2.z + W3*u3.z;             \
  ao.w = W0*u0.w + W1*u1.w + W2*u2.w + W3*u3.w;             \
  dd.x = W3*u0.x - W2*u1.x + W1*u2.x - W0*u3.x;             \
  dd.y = W3*u0.y - W2*u1.y + W1*u2.y - W0*u3.y;             \
  dd.z = W3*u0.z - W2*u1.z + W1*u2.z - W0*u3.z;             \
  dd.w = W3*u0.w - W2*u1.w + W1*u2.w - W0*u3.w;
  DWT_AD(a0, d0, v[0], v[1], v[2], v[3]);
  DWT_AD(a1, d1, v[2], v[3], v[4], v[5]);
#undef DWT_AD

  const size_t rowA = (size_t)b * AROWS + 1 + m;
  const size_t rowD = (size_t)(b + 8) * AROWS + 1 + m;
  *reinterpret_cast<ushort4*>(&A[rowA * Hc + h4]) = rnd4(a0);
  *reinterpret_cast<ushort4*>(&A[(rowA + 1) * Hc + h4]) = rnd4(a1);
  *reinterpret_cast<ushort4*>(&A[rowD * Hc + h4]) = rnd4(d0);
  *reinterpret_cast<ushort4*>(&A[(rowD + 1) * Hc + h4]) = rnd4(d1);

  if (mp == 0) {  // zero the 4 guard rows this (b,h4) owns
    const ushort4 z4 = {0, 0, 0, 0};
    const size_t gr[4] = {(size_t)b * AROWS,       (size_t)b * AROWS + AROWS - 1,
                          (size_t)(b + 8) * AROWS, (size_t)(b + 8) * AROWS + AROWS - 1};
#pragma unroll
    for (int i = 0; i < 4; ++i)
      *reinterpret_cast<ushort4*>(&A[gr[i] * Hc + h4]) = z4;
  }
}

// ---------------------------------------------------------------- weight prep
__global__ void prep_conv_w(const float* __restrict__ wA, const float* __restrict__ wD,
                            unsigned short* __restrict__ aH, unsigned short* __restrict__ aL,
                            unsigned short* __restrict__ dH, unsigned short* __restrict__ dL) {
  const int idx = blockIdx.x * 256 + threadIdx.x;  // 2*1024*256
  const int i4 = idx & 255;
  const int o = (idx >> 8) & 1023;
  const int c = idx >> 18;
  const float* w = c ? wD : wA;
  unsigned short* oh = c ? dH : aH;
  unsigned short* ol = c ? dL : aL;
  const float* src = w + (size_t)o * 3072 + i4 * 12;
  const float4 f0 = *reinterpret_cast<const float4*>(src);
  const float4 f1 = *reinterpret_cast<const float4*>(src + 4);
  const float4 f2 = *reinterpret_cast<const float4*>(src + 8);
  const float e[12] = {f0.x, f0.y, f0.z, f0.w, f1.x, f1.y, f1.z, f1.w,
                       f2.x, f2.y, f2.z, f2.w};
#pragma unroll
  for (int k = 0; k < 3; ++k) {
    float4 v = make_float4(e[k], e[3 + k], e[6 + k], e[9 + k]);
    ushort4 hh, ll;
    split4(v, hh, ll);
    const size_t off = (size_t)k * 1048576 + (size_t)o * 1024 + i4 * 4;
    *reinterpret_cast<ushort4*>(&oh[off]) = hh;
    *reinterpret_cast<ushort4*>(&ol[off]) = ll;
  }
}

__global__ void prep_wout(const float* __restrict__ w,
                          unsigned short* __restrict__ oh, unsigned short* __restrict__ ol) {
  const int idx = blockIdx.x * 256 + threadIdx.x;  // 1024*256
  const size_t off = (size_t)(idx >> 8) * 1024 + (idx & 255) * 4;
  ushort4 hh, ll;
  split4(*reinterpret_cast<const float4*>(&w[off]), hh, ll);
  *reinterpret_cast<ushort4*>(&oh[off]) = hh;
  *reinterpret_cast<ushort4*>(&ol[off]) = ll;
}

// ---------------------------------------------------------------- conv MFMA
// BM=256 x BN=128, 512 threads (8 waves, 2 wm x 4 wn; wave = 128 rows x 32
// cols, acc 8x2). Tap-shared A (258 rows). T3-min pipeline: LDS double
// buffer; per k-step STAGE(next) -> compute(cur) -> one __syncthreads.
// Grid 512: t = id&3, o = (id>>2)&7, z = id>>5.
__global__ __launch_bounds__(512, 2) void conv_mm_kernel(
    const unsigned short* __restrict__ A,
    const unsigned short* __restrict__ BAh, const unsigned short* __restrict__ BAl,
    const unsigned short* __restrict__ BDh, const unsigned short* __restrict__ BDl,
    const float* __restrict__ biasA, const float* __restrict__ biasD,
    float* __restrict__ Yout) {
  // per buffer (ushorts): As[258][32] @0 (8256), Bs[tp][128][32] @8256+tp*4096
  // buffer stride 32832 ushorts; total 2 buffers = 131,328 B
  __shared__ __align__(16) unsigned short lds[65664];

  const int tid = threadIdx.x;
  const int lane = tid & 63;
  const int wave = tid >> 6;           // 0..7
  const int wm = wave >> 2;            // 0..1
  const int wn = wave & 3;             // 0..3

  const int id = blockIdx.x;
  const int t = id & 3;
  const int o = (id >> 2) & 7;
  const int z = id >> 5;               // 0..15
  const int o0 = o * 128;
  const int t0 = t * 256;
  const int arow0 = z * AROWS + t0;

  const unsigned short* BH = (z < 8) ? BAh : BDh;
  const unsigned short* BL = (z < 8) ? BAl : BDl;
  const float* bias = (z < 8) ? biasA : biasD;

  f32x4 acc[8][2];
#pragma unroll
  for (int m = 0; m < 8; ++m)
#pragma unroll
    for (int n = 0; n < 2; ++n) acc[m][n] = (f32x4){0.f, 0.f, 0.f, 0.f};

  const int q = lane >> 2;
  const int srcslot = (lane & 3) ^ ((lane >> 3) & 3);  // pre-swizzled source slot
  const int l15 = lane & 15;
  const int g = lane >> 4;

#define CONV_STAGE(buf, c0)                                                     \
  {                                                                             \
    unsigned short* L = lds + (buf) * 32832;                                    \
    _Pragma("unroll")                                                           \
    for (int j = 0; j < 2; ++j) {                                               \
      const int seg = wave * 2 + j;                                             \
      const int r = seg * 16 + q;                                               \
      gload16(A + (size_t)(arow0 + r) * 1024 + (c0) + srcslot * 8,              \
              L + seg * 512);                                                   \
    }                                                                           \
    if (wave == 0 && lane < 8) {                                                \
      const int r = 256 + (lane >> 2);                                          \
      gload16(A + (size_t)(arow0 + r) * 1024 + (c0) + (lane & 3) * 8,           \
              L + 8192);                                                        \
    }                                                                           \
    _Pragma("unroll")                                                           \
    for (int j = 0; j < 6; ++j) {                                               \
      const int g6 = wave * 6 + j;                                              \
      const int tp = g6 >> 3;                                                   \
      const int seg = g6 & 7;                                                   \
      const unsigned short* bp =                                                \
          ((tp & 1) ? BL : BH) + (size_t)(tp >> 1) * 1048576;                   \
      const int r = seg * 16 + q;                                               \
      gload16(bp + (size_t)(o0 + r) * 1024 + (c0) + srcslot * 8,                \
              L + 8256 + tp * 4096 + seg * 512);                                \
    }                                                                           \
  }

  CONV_STAGE(0, 0);
  __syncthreads();

  int cur = 0;
#pragma unroll 1
  for (int step = 0; step < 32; ++step) {
    if (step < 31) CONV_STAGE(cur ^ 1, (step + 1) * 32);

    unsigned short* L = lds + cur * 32832;
#pragma unroll
    for (int tap = 0; tap < 3; ++tap) {
      bf16x8 a4[8];
#pragma unroll
      for (int m = 0; m < 8; ++m) {
        const int r = wm * 128 + m * 16 + l15 + tap;
        a4[m] = *reinterpret_cast<const bf16x8*>(L + r * 32 + (g ^ ((r >> 1) & 3)) * 8);
      }
#pragma unroll
      for (int n = 0; n < 2; ++n) {
        const int r = wn * 32 + n * 16 + l15;
        const int off = r * 32 + (g ^ ((r >> 1) & 3)) * 8;
        const bf16x8 bH4 = *reinterpret_cast<const bf16x8*>(L + 8256 + (tap * 2) * 4096 + off);
        const bf16x8 bL4 = *reinterpret_cast<const bf16x8*>(L + 8256 + (tap * 2 + 1) * 4096 + off);
#pragma unroll
        for (int m = 0; m < 8; ++m) {
          acc[m][n] = __builtin_amdgcn_mfma_f32_16x16x32_bf16(a4[m], bH4, acc[m][n], 0, 0, 0);
          acc[m][n] = __builtin_amdgcn_mfma_f32_16x16x32_bf16(a4[m], bL4, acc[m][n], 0, 0, 0);
        }
      }
    }
    __syncthreads();  // drains staged loads (covered by compute) + read-done
    cur ^= 1;
  }
#undef CONV_STAGE

  // epilogue: C/D frag col = lane&15, row = (lane>>4)*4 + reg  [m89]
  const int yrow0 = z * Mcv + t0 + wm * 128;
  constexpr float RS2 = 0.70710678118654752440f;
#pragma unroll
  for (int n = 0; n < 2; ++n) {
    const int col = o0 + wn * 32 + n * 16 + l15;
    const float bv = bias[col];
#pragma unroll
    for (int m = 0; m < 8; ++m) {
      const int rbase = yrow0 + m * 16 + g * 4;
#pragma unroll
      for (int r = 0; r < 4; ++r) {
        float v = acc[m][n][r] + bv;
        v = 0.5f * v * (1.f + erff(v * RS2));
        Yout[(size_t)(rbase + r) * 1024 + col] = v;
      }
    }
  }
}

// ---------------------------------------------------------------- IDWT
// Paired: each thread computes s=2j and s=2j+1 from the SAME 4 plane rows.
// pout batches 0..7 = pa, 8..15 = pd. Output: single rounded bf16 plane.
__global__ void idwt_kernel(const float* __restrict__ pout,
                            unsigned short* __restrict__ rc) {
  const int tid = blockIdx.x * 256 + threadIdx.x;  // 2^21 threads
  const int h4 = (tid & 255) << 2;
  const int j = (tid >> 8) & 1023;
  const int b = tid >> 18;
  const size_t ro = ((size_t)b * Sc + 2 * j) * Hc + h4;
  if (j == 1023) {  // s = 2046, 2047: zero padding rows
    const ushort4 z4 = {0, 0, 0, 0};
    *reinterpret_cast<ushort4*>(&rc[ro]) = z4;
    *reinterpret_cast<ushort4*>(&rc[ro + Hc]) = z4;
    return;
  }
  const float* pab = pout + (size_t)b * Mcv * Hc;
  const float* pdb = pout + (size_t)(b + 8) * Mcv * Hc;
  const float4 aL = *reinterpret_cast<const float4*>(&pab[(size_t)j * Hc + h4]);
  const float4 aH = *reinterpret_cast<const float4*>(&pab[(size_t)(j + 1) * Hc + h4]);
  const float4 dL = *reinterpret_cast<const float4*>(&pdb[(size_t)j * Hc + h4]);
  const float4 dH = *reinterpret_cast<const float4*>(&pdb[(size_t)(j + 1) * Hc + h4]);
  float4 r0, r1;
  r0.x = W0 * aH.x + W2 * aL.x + W3 * dH.x + W1 * dL.x;
  r0.y = W0 * aH.y + W2 * aL.y + W3 * dH.y + W1 * dL.y;
  r0.z = W0 * aH.z + W2 * aL.z + W3 * dH.z + W1 * dL.z;
  r0.w = W0 * aH.w + W2 * aL.w + W3 * dH.w + W1 * dL.w;
  r1.x = W1 * aH.x + W3 * aL.x - W2 * dH.x - W0 * dL.x;
  r1.y = W1 * aH.y + W3 * aL.y - W2 * dH.y - W0 * dL.y;
  r1.z = W1 * aH.z + W3 * aL.z - W2 * dH.z - W0 * dL.z;
  r1.w = W1 * aH.w + W3 * aL.w - W2 * dH.w - W0 * dL.w;
  *reinterpret_cast<ushort4*>(&rc[ro]) = rnd4(r0);
  *reinterpret_cast<ushort4*>(&rc[ro + Hc]) = rnd4(r1);
}

// ---------------------------------------------------------------- out GEMM
// BM=256 x BN=128, 256 threads (4 waves 2x2, acc 8x4/wave). T3-min pipeline,
// LDS double buffer (2 x 32 KB -> 2 blocks/CU).
// Grid 512: rowt = (id>>6)*8 + (id&7), col = (id>>3)&7.
__global__ __launch_bounds__(256, 2) void gemm_out_kernel(
    const unsigned short* __restrict__ Arc,
    const unsigned short* __restrict__ Bhi, const unsigned short* __restrict__ Blo,
    const float* __restrict__ bias, float* __restrict__ out) {
  // per buffer (ushorts): As[256][32] @0 (8192), BsH @8192, BsL @12288;
  // buffer stride 16384 ushorts; total 65,536 B
  __shared__ __align__(16) unsigned short lds[32768];

  const int tid = threadIdx.x;
  const int lane = tid & 63;
  const int wave = tid >> 6;
  const int wm = wave >> 1, wn = wave & 1;

  const int id = blockIdx.x;
  const int rowt = (id >> 6) * 8 + (id & 7);  // 0..63
  const int col = (id >> 3) & 7;
  const int o0 = col * 128;
  const int t0 = rowt * 256;

  f32x4 acc[8][4];
#pragma unroll
  for (int m = 0; m < 8; ++m)
#pragma unroll
    for (int n = 0; n < 4; ++n) acc[m][n] = (f32x4){0.f, 0.f, 0.f, 0.f};

  const int q = lane >> 2;
  const int srcslot = (lane & 3) ^ ((lane >> 3) & 3);
  const int l15 = lane & 15;
  const int g = lane >> 4;

#define GEMM_STAGE(buf, c0)                                                     \
  {                                                                             \
    unsigned short* L = lds + (buf) * 16384;                                    \
    _Pragma("unroll")                                                           \
    for (int j = 0; j < 4; ++j) {                                               \
      const int seg = wave * 4 + j;                                             \
      const int r = seg * 16 + q;                                               \
      gload16(Arc + (size_t)(t0 + r) * 1024 + (c0) + srcslot * 8,               \
              L + seg * 512);                                                   \
    }                                                                           \
    _Pragma("unroll")                                                           \
    for (int j = 0; j < 4; ++j) {                                               \
      const int g4 = wave * 4 + j;                                              \
      const int pl = g4 >> 3;                                                   \
      const int seg = g4 & 7;                                                   \
      const unsigned short* bp = pl ? Blo : Bhi;                                \
      const int r = seg * 16 + q;                                               \
      gload16(bp + (size_t)(o0 + r) * 1024 + (c0) + srcslot * 8,                \
              L + 8192 + pl * 4096 + seg * 512);                                \
    }                                                                           \
  }

  GEMM_STAGE(0, 0);
  __syncthreads();

  int cur = 0;
#pragma unroll 1
  for (int step = 0; step < 32; ++step) {
    if (step < 31) GEMM_STAGE(cur ^ 1, (step + 1) * 32);

    unsigned short* L = lds + cur * 16384;
    bf16x8 a4[8], bH4[4], bL4[4];
#pragma unroll
    for (int m = 0; m < 8; ++m) {
      const int r = wm * 128 + m * 16 + l15;
      a4[m] = *reinterpret_cast<const bf16x8*>(L + r * 32 + (g ^ ((r >> 1) & 3)) * 8);
    }
#pragma unroll
    for (int n = 0; n < 4; ++n) {
      const int r = wn * 64 + n * 16 + l15;
      const int off = r * 32 + (g ^ ((r >> 1) & 3)) * 8;
      bH4[n] = *reinterpret_cast<const bf16x8*>(L + 8192 + off);
      bL4[n] = *reinterpret_cast<const bf16x8*>(L + 12288 + off);
    }
#pragma unroll
    for (int m = 0; m < 8; ++m)
#pragma unroll
      for (int n = 0; n < 4; ++n) {
        acc[m][n] = __builtin_amdgcn_mfma_f32_16x16x32_bf16(a4[m], bH4[n], acc[m][n], 0, 0, 0);
        acc[m][n] = __builtin_amdgcn_mfma_f32_16x16x32_bf16(a4[m], bL4[n], acc[m][n], 0, 0, 0);
      }
    __syncthreads();
    cur ^= 1;
  }
#undef GEMM_STAGE

  const int yrow0 = t0 + wm * 128;
#pragma unroll
  for (int n = 0; n < 4; ++n) {
    const int colg = o0 + wn * 64 + n * 16 + l15;
    const float bv = bias[colg];
#pragma unroll
    for (int m = 0; m < 8; ++m) {
      const int rbase = yrow0 + m * 16 + g * 4;
#pragma unroll
      for (int r = 0; r < 4; ++r)
        out[(size_t)(rbase + r) * 1024 + colg] = acc[m][n][r] + bv;
    }
  }
}

}  // namespace

extern "C" void kernel_launch(void* const* d_in, const int* in_sizes, int n_in,
                              void* d_out, int out_size, void* d_ws, size_t ws_size,
                              hipStream_t stream) {
  const float* x = (const float*)d_in[0];
  const float* w_approx = (const float*)d_in[1];
  const float* b_approx = (const float*)d_in[2];
  const float* w_detail = (const float*)d_in[3];
  const float* b_detail = (const float*)d_in[4];
  const float* w_out = (const float*)d_in[5];
  const float* b_out = (const float*)d_in[6];
  float* out = (float*)d_out;

  char* ws = (char*)d_ws;
  // merged A plane: 16 batches x 1026 rows x 1024 ushorts = 33,619,968 B
  unsigned short* A = (unsigned short*)(ws);
  float* pout = (float*)(ws + 33619968);                     // 16x1024x1024 f32 = 67,108,864 B
  unsigned short* rc = (unsigned short*)(ws + 100728832);    // 16384x1024 ushorts = 33,554,432 B
  unsigned short* wtAh = (unsigned short*)(ws + 134348800);  // 6,291,456 B each
  unsigned short* wtAl = (unsigned short*)(ws + 140640256);
  unsigned short* wtDh = (unsigned short*)(ws + 146931712);
  unsigned short* wtDl = (unsigned short*)(ws + 153223168);
  unsigned short* woH = (unsigned short*)(ws + 159514624);   // 2,097,152 B each
  unsigned short* woL = (unsigned short*)(ws + 161611776);

  prep_conv_w<<<2048, 256, 0, stream>>>(w_approx, w_detail, wtAh, wtAl, wtDh, wtDl);
  prep_wout<<<1024, 256, 0, stream>>>(w_out, woH, woL);
  dwt_kernel<<<4096, 256, 0, stream>>>(x, A);

  conv_mm_kernel<<<512, 512, 0, stream>>>(A, wtAh, wtAl, wtDh, wtDl,
                                          b_approx, b_detail, pout);

  idwt_kernel<<<8192, 256, 0, stream>>>(pout, rc);

  gemm_out_kernel<<<512, 256, 0, stream>>>(rc, woH, woL, b_out, out);
}

// Round 12
// 384.661 us; speedup vs baseline: 4.9474x; 1.0630x over previous
//
#include <hip/hip_runtime.h>
#include <hip/hip_bf16.h>
#include <math.h>

// WaveletLayer: DWT(db2) -> conv3+GELU (x2) -> IDWT -> out-projection.
// Round 12 (= Round 11 resubmit; bench infra timed out): (1) out-GEMM
// re-tiled to 256x256 / 512 thr / 8 waves (staging 96 B/MFMA, grid 256 = 1
// residency round, XCD-chunked swizzle); (2) pout stored as bf16 (conv
// epilogue + idwt read). Conv unchanged from R10 (T3-min pipeline).

namespace {

constexpr int Hc = 1024;
constexpr int Sc = 2048;
constexpr int Mcv = 1024;   // conv seq len (S/2)
constexpr int AROWS = 1026; // conv A rows per batch-plane (1 guard each side)

constexpr double S3d = 1.7320508075688772935274463;
constexpr double DNd = 5.6568542494923801952067549;  // 4*sqrt(2)
constexpr float W0 = (float)((1.0 + S3d) / DNd);
constexpr float W1 = (float)((3.0 + S3d) / DNd);
constexpr float W2 = (float)((3.0 - S3d) / DNd);
constexpr float W3 = (float)((1.0 - S3d) / DNd);

typedef short bf16x8 __attribute__((ext_vector_type(8)));
typedef unsigned short u16x8 __attribute__((ext_vector_type(8)));
typedef float f32x4 __attribute__((ext_vector_type(4)));

typedef __attribute__((address_space(1))) const unsigned char ga_u8;
typedef __attribute__((address_space(3))) unsigned char la_u8;

__device__ __forceinline__ void gload16(const void* g, void* l) {
  __builtin_amdgcn_global_load_lds((ga_u8*)g, (la_u8*)l, 16, 0, 0);
}

__device__ __forceinline__ unsigned short rnd1(float v) {
  __hip_bfloat16 hb = __float2bfloat16(v);
  return *reinterpret_cast<unsigned short*>(&hb);
}

__device__ __forceinline__ float b2f(unsigned short s) {
  union { unsigned int u; float f; } c;
  c.u = ((unsigned int)s) << 16;
  return c.f;
}

__device__ __forceinline__ ushort4 rnd4(const float4 v) {
  ushort4 h;
  h.x = rnd1(v.x); h.y = rnd1(v.y); h.z = rnd1(v.z); h.w = rnd1(v.w);
  return h;
}

__device__ __forceinline__ void split1(float v, unsigned short& h, unsigned short& l) {
  __hip_bfloat16 hb = __float2bfloat16(v);
  float r = v - __bfloat162float(hb);
  __hip_bfloat16 lb = __float2bfloat16(r);
  h = *reinterpret_cast<unsigned short*>(&hb);
  l = *reinterpret_cast<unsigned short*>(&lb);
}

__device__ __forceinline__ void split4(const float4 v, ushort4& h, ushort4& l) {
  split1(v.x, h.x, l.x);
  split1(v.y, h.y, l.y);
  split1(v.z, h.z, l.z);
  split1(v.w, h.w, l.w);
}

// ---------------------------------------------------------------- DWT
// Paired: each thread computes m and m+1 (6 x-rows instead of 8).
// Merged A buffer, single bf16 plane: batches 0..7 = ca, 8..15 = cd.
__global__ void dwt_kernel(const float* __restrict__ x,
                           unsigned short* __restrict__ A) {
  const int tid = blockIdx.x * 256 + threadIdx.x;  // 2^20 threads
  const int h4 = (tid & 255) << 2;
  const int mp = (tid >> 8) & 511;
  const int b = tid >> 17;
  const int m = mp * 2;
  const float* xb = x + (size_t)b * Sc * Hc;
  float4 v[6];
#pragma unroll
  for (int t = 0; t < 6; ++t) {
    int i = 2 * m - 2 + t;
    if (i < 0) i = -i - 1;  // symmetric left reflection
    v[t] = *reinterpret_cast<const float4*>(&xb[(size_t)i * Hc + h4]);
  }
  float4 a0, d0, a1, d1;
#define DWT_AD(ao, dd, u0, u1, u2, u3)                      \
  ao.x = W0*u0.x + W1*u1.x + W2*u2.x + W3*u3.x;             \
  ao.y = W0*u0.y + W1*u1.y + W2*u2.y + W3*u3.y;             \
  ao.z = W0*u0.z + W1*u1.z + W2*u2.z + W3*u3.z;             \
  ao.w = W0*u0.w + W1*u1.w + W2*u2.w + W3*u3.w;             \
  dd.x = W3*u0.x - W2*u1.x + W1*u2.x - W0*u3.x;             \
  dd.y = W3*u0.y - W2*u1.y + W1*u2.y - W0*u3.y;             \
  dd.z = W3*u0.z - W2*u1.z + W1*u2.z - W0*u3.z;             \
  dd.w = W3*u0.w - W2*u1.w + W1*u2.w - W0*u3.w;
  DWT_AD(a0, d0, v[0], v[1], v[2], v[3]);
  DWT_AD(a1, d1, v[2], v[3], v[4], v[5]);
#undef DWT_AD

  const size_t rowA = (size_t)b * AROWS + 1 + m;
  const size_t rowD = (size_t)(b + 8) * AROWS + 1 + m;
  *reinterpret_cast<ushort4*>(&A[rowA * Hc + h4]) = rnd4(a0);
  *reinterpret_cast<ushort4*>(&A[(rowA + 1) * Hc + h4]) = rnd4(a1);
  *reinterpret_cast<ushort4*>(&A[rowD * Hc + h4]) = rnd4(d0);
  *reinterpret_cast<ushort4*>(&A[(rowD + 1) * Hc + h4]) = rnd4(d1);

  if (mp == 0) {  // zero the 4 guard rows this (b,h4) owns
    const ushort4 z4 = {0, 0, 0, 0};
    const size_t gr[4] = {(size_t)b * AROWS,       (size_t)b * AROWS + AROWS - 1,
                          (size_t)(b + 8) * AROWS, (size_t)(b + 8) * AROWS + AROWS - 1};
#pragma unroll
    for (int i = 0; i < 4; ++i)
      *reinterpret_cast<ushort4*>(&A[gr[i] * Hc + h4]) = z4;
  }
}

// ---------------------------------------------------------------- weight prep
__global__ void prep_conv_w(const float* __restrict__ wA, const float* __restrict__ wD,
                            unsigned short* __restrict__ aH, unsigned short* __restrict__ aL,
                            unsigned short* __restrict__ dH, unsigned short* __restrict__ dL) {
  const int idx = blockIdx.x * 256 + threadIdx.x;  // 2*1024*256
  const int i4 = idx & 255;
  const int o = (idx >> 8) & 1023;
  const int c = idx >> 18;
  const float* w = c ? wD : wA;
  unsigned short* oh = c ? dH : aH;
  unsigned short* ol = c ? dL : aL;
  const float* src = w + (size_t)o * 3072 + i4 * 12;
  const float4 f0 = *reinterpret_cast<const float4*>(src);
  const float4 f1 = *reinterpret_cast<const float4*>(src + 4);
  const float4 f2 = *reinterpret_cast<const float4*>(src + 8);
  const float e[12] = {f0.x, f0.y, f0.z, f0.w, f1.x, f1.y, f1.z, f1.w,
                       f2.x, f2.y, f2.z, f2.w};
#pragma unroll
  for (int k = 0; k < 3; ++k) {
    float4 v = make_float4(e[k], e[3 + k], e[6 + k], e[9 + k]);
    ushort4 hh, ll;
    split4(v, hh, ll);
    const size_t off = (size_t)k * 1048576 + (size_t)o * 1024 + i4 * 4;
    *reinterpret_cast<ushort4*>(&oh[off]) = hh;
    *reinterpret_cast<ushort4*>(&ol[off]) = ll;
  }
}

__global__ void prep_wout(const float* __restrict__ w,
                          unsigned short* __restrict__ oh, unsigned short* __restrict__ ol) {
  const int idx = blockIdx.x * 256 + threadIdx.x;  // 1024*256
  const size_t off = (size_t)(idx >> 8) * 1024 + (idx & 255) * 4;
  ushort4 hh, ll;
  split4(*reinterpret_cast<const float4*>(&w[off]), hh, ll);
  *reinterpret_cast<ushort4*>(&oh[off]) = hh;
  *reinterpret_cast<ushort4*>(&ol[off]) = ll;
}

// ---------------------------------------------------------------- conv MFMA
// BM=256 x BN=128, 512 threads (8 waves, 2 wm x 4 wn; wave = 128 rows x 32
// cols, acc 8x2). Tap-shared A (258 rows). T3-min pipeline: LDS double
// buffer; per k-step STAGE(next) -> compute(cur) -> one __syncthreads.
// Grid 512: t = id&3, o = (id>>2)&7, z = id>>5. Output pout is bf16.
__global__ __launch_bounds__(512, 2) void conv_mm_kernel(
    const unsigned short* __restrict__ A,
    const unsigned short* __restrict__ BAh, const unsigned short* __restrict__ BAl,
    const unsigned short* __restrict__ BDh, const unsigned short* __restrict__ BDl,
    const float* __restrict__ biasA, const float* __restrict__ biasD,
    unsigned short* __restrict__ Yout) {
  // per buffer (ushorts): As[258][32] @0 (8256), Bs[tp][128][32] @8256+tp*4096
  // buffer stride 32832 ushorts; total 2 buffers = 131,328 B
  __shared__ __align__(16) unsigned short lds[65664];

  const int tid = threadIdx.x;
  const int lane = tid & 63;
  const int wave = tid >> 6;           // 0..7
  const int wm = wave >> 2;            // 0..1
  const int wn = wave & 3;             // 0..3

  const int id = blockIdx.x;
  const int t = id & 3;
  const int o = (id >> 2) & 7;
  const int z = id >> 5;               // 0..15
  const int o0 = o * 128;
  const int t0 = t * 256;
  const int arow0 = z * AROWS + t0;

  const unsigned short* BH = (z < 8) ? BAh : BDh;
  const unsigned short* BL = (z < 8) ? BAl : BDl;
  const float* bias = (z < 8) ? biasA : biasD;

  f32x4 acc[8][2];
#pragma unroll
  for (int m = 0; m < 8; ++m)
#pragma unroll
    for (int n = 0; n < 2; ++n) acc[m][n] = (f32x4){0.f, 0.f, 0.f, 0.f};

  const int q = lane >> 2;
  const int srcslot = (lane & 3) ^ ((lane >> 3) & 3);  // pre-swizzled source slot
  const int l15 = lane & 15;
  const int g = lane >> 4;

#define CONV_STAGE(buf, c0)                                                     \
  {                                                                             \
    unsigned short* L = lds + (buf) * 32832;                                    \
    _Pragma("unroll")                                                           \
    for (int j = 0; j < 2; ++j) {                                               \
      const int seg = wave * 2 + j;                                             \
      const int r = seg * 16 + q;                                               \
      gload16(A + (size_t)(arow0 + r) * 1024 + (c0) + srcslot * 8,              \
              L + seg * 512);                                                   \
    }                                                                           \
    if (wave == 0 && lane < 8) {                                                \
      const int r = 256 + (lane >> 2);                                          \
      gload16(A + (size_t)(arow0 + r) * 1024 + (c0) + (lane & 3) * 8,           \
              L + 8192);                                                        \
    }                                                                           \
    _Pragma("unroll")                                                           \
    for (int j = 0; j < 6; ++j) {                                               \
      const int g6 = wave * 6 + j;                                              \
      const int tp = g6 >> 3;                                                   \
      const int seg = g6 & 7;                                                   \
      const unsigned short* bp =                                                \
          ((tp & 1) ? BL : BH) + (size_t)(tp >> 1) * 1048576;                   \
      const int r = seg * 16 + q;                                               \
      gload16(bp + (size_t)(o0 + r) * 1024 + (c0) + srcslot * 8,                \
              L + 8256 + tp * 4096 + seg * 512);                                \
    }                                                                           \
  }

  CONV_STAGE(0, 0);
  __syncthreads();

  int cur = 0;
#pragma unroll 1
  for (int step = 0; step < 32; ++step) {
    if (step < 31) CONV_STAGE(cur ^ 1, (step + 1) * 32);

    unsigned short* L = lds + cur * 32832;
#pragma unroll
    for (int tap = 0; tap < 3; ++tap) {
      bf16x8 a4[8];
#pragma unroll
      for (int m = 0; m < 8; ++m) {
        const int r = wm * 128 + m * 16 + l15 + tap;
        a4[m] = *reinterpret_cast<const bf16x8*>(L + r * 32 + (g ^ ((r >> 1) & 3)) * 8);
      }
#pragma unroll
      for (int n = 0; n < 2; ++n) {
        const int r = wn * 32 + n * 16 + l15;
        const int off = r * 32 + (g ^ ((r >> 1) & 3)) * 8;
        const bf16x8 bH4 = *reinterpret_cast<const bf16x8*>(L + 8256 + (tap * 2) * 4096 + off);
        const bf16x8 bL4 = *reinterpret_cast<const bf16x8*>(L + 8256 + (tap * 2 + 1) * 4096 + off);
#pragma unroll
        for (int m = 0; m < 8; ++m) {
          acc[m][n] = __builtin_amdgcn_mfma_f32_16x16x32_bf16(a4[m], bH4, acc[m][n], 0, 0, 0);
          acc[m][n] = __builtin_amdgcn_mfma_f32_16x16x32_bf16(a4[m], bL4, acc[m][n], 0, 0, 0);
        }
      }
    }
    __syncthreads();  // drains staged loads (covered by compute) + read-done
    cur ^= 1;
  }
#undef CONV_STAGE

  // epilogue: C/D frag col = lane&15, row = (lane>>4)*4 + reg  [m89]
  const int yrow0 = z * Mcv + t0 + wm * 128;
  constexpr float RS2 = 0.70710678118654752440f;
#pragma unroll
  for (int n = 0; n < 2; ++n) {
    const int col = o0 + wn * 32 + n * 16 + l15;
    const float bv = bias[col];
#pragma unroll
    for (int m = 0; m < 8; ++m) {
      const int rbase = yrow0 + m * 16 + g * 4;
#pragma unroll
      for (int r = 0; r < 4; ++r) {
        float v = acc[m][n][r] + bv;
        v = 0.5f * v * (1.f + erff(v * RS2));
        Yout[(size_t)(rbase + r) * 1024 + col] = rnd1(v);
      }
    }
  }
}

// ---------------------------------------------------------------- IDWT
// Paired + bf16 input: thread computes s=2j, 2j+1 for 8 h-columns from the
// SAME 4 bf16 plane rows. pout batches 0..7 = pa, 8..15 = pd.
__global__ void idwt_kernel(const unsigned short* __restrict__ pout,
                            unsigned short* __restrict__ rc) {
  const int tid = blockIdx.x * 256 + threadIdx.x;  // 2^20 threads
  const int h8 = (tid & 127) << 3;
  const int j = (tid >> 7) & 1023;
  const int b = tid >> 17;  // 0..7
  const size_t ro = ((size_t)b * Sc + 2 * j) * Hc + h8;
  if (j == 1023) {  // s = 2046, 2047: zero padding rows
    const u16x8 z8 = {0, 0, 0, 0, 0, 0, 0, 0};
    *reinterpret_cast<u16x8*>(&rc[ro]) = z8;
    *reinterpret_cast<u16x8*>(&rc[ro + Hc]) = z8;
    return;
  }
  const unsigned short* pab = pout + (size_t)b * Mcv * Hc;
  const unsigned short* pdb = pout + (size_t)(b + 8) * Mcv * Hc;
  const u16x8 aL = *reinterpret_cast<const u16x8*>(&pab[(size_t)j * Hc + h8]);
  const u16x8 aH = *reinterpret_cast<const u16x8*>(&pab[(size_t)(j + 1) * Hc + h8]);
  const u16x8 dL = *reinterpret_cast<const u16x8*>(&pdb[(size_t)j * Hc + h8]);
  const u16x8 dH = *reinterpret_cast<const u16x8*>(&pdb[(size_t)(j + 1) * Hc + h8]);
  u16x8 r0, r1;
#pragma unroll
  for (int e = 0; e < 8; ++e) {
    const float faL = b2f(aL[e]), faH = b2f(aH[e]);
    const float fdL = b2f(dL[e]), fdH = b2f(dH[e]);
    r0[e] = rnd1(W0 * faH + W2 * faL + W3 * fdH + W1 * fdL);
    r1[e] = rnd1(W1 * faH + W3 * faL - W2 * fdH - W0 * fdL);
  }
  *reinterpret_cast<u16x8*>(&rc[ro]) = r0;
  *reinterpret_cast<u16x8*>(&rc[ro + Hc]) = r1;
}

// ---------------------------------------------------------------- out GEMM
// BM=256 x BN=256, 512 threads (8 waves 2x4, acc 8x4/wave = 128x64 out).
// T3-min pipeline, LDS dbuf 2 x 48 KB. Grid 256 = exactly 1 residency round.
// XCD-chunked swizzle: wgid = (id&7)*32 + id>>3 -> XCD x owns row-panels
// [8x, 8x+8) with all 4 col-blocks of each panel on the same XCD.
__global__ __launch_bounds__(512, 2) void gemm_out_kernel(
    const unsigned short* __restrict__ Arc,
    const unsigned short* __restrict__ Bhi, const unsigned short* __restrict__ Blo,
    const float* __restrict__ bias, float* __restrict__ out) {
  // per buffer (ushorts): As[256][32] @0 (8192), BsH[256][32] @8192, BsL @16384
  // buffer stride 24576 ushorts; total 2 buffers = 98,304 B
  __shared__ __align__(16) unsigned short lds[49152];

  const int tid = threadIdx.x;
  const int lane = tid & 63;
  const int wave = tid >> 6;          // 0..7
  const int wm = wave >> 2;           // 0..1
  const int wn = wave & 3;            // 0..3

  const int id = blockIdx.x;                     // 0..255
  const int wgid = (id & 7) * 32 + (id >> 3);    // bijective XCD chunking
  const int rowt = wgid >> 2;                    // 0..63
  const int colt = wgid & 3;                     // 0..3
  const int o0 = colt * 256;
  const int t0 = rowt * 256;

  f32x4 acc[8][4];
#pragma unroll
  for (int m = 0; m < 8; ++m)
#pragma unroll
    for (int n = 0; n < 4; ++n) acc[m][n] = (f32x4){0.f, 0.f, 0.f, 0.f};

  const int q = lane >> 2;
  const int srcslot = (lane & 3) ^ ((lane >> 3) & 3);
  const int l15 = lane & 15;
  const int g = lane >> 4;

#define GEMM_STAGE(buf, c0)                                                     \
  {                                                                             \
    unsigned short* L = lds + (buf) * 24576;                                    \
    _Pragma("unroll")                                                           \
    for (int j = 0; j < 2; ++j) {                                               \
      const int seg = wave * 2 + j;                                             \
      const int r = seg * 16 + q;                                               \
      gload16(Arc + (size_t)(t0 + r) * 1024 + (c0) + srcslot * 8,               \
              L + seg * 512);                                                   \
    }                                                                           \
    _Pragma("unroll")                                                           \
    for (int j = 0; j < 4; ++j) {                                               \
      const int g4 = wave * 4 + j;                                              \
      const int pl = g4 >> 4;                                                   \
      const int seg = g4 & 15;                                                  \
      const unsigned short* bp = pl ? Blo : Bhi;                                \
      const int r = seg * 16 + q;                                               \
      gload16(bp + (size_t)(o0 + r) * 1024 + (c0) + srcslot * 8,                \
              L + 8192 + pl * 8192 + seg * 512);                                \
    }                                                                           \
  }

  GEMM_STAGE(0, 0);
  __syncthreads();

  int cur = 0;
#pragma unroll 1
  for (int step = 0; step < 32; ++step) {
    if (step < 31) GEMM_STAGE(cur ^ 1, (step + 1) * 32);

    unsigned short* L = lds + cur * 24576;
    bf16x8 a4[8], bH4[4], bL4[4];
#pragma unroll
    for (int m = 0; m < 8; ++m) {
      const int r = wm * 128 + m * 16 + l15;
      a4[m] = *reinterpret_cast<const bf16x8*>(L + r * 32 + (g ^ ((r >> 1) & 3)) * 8);
    }
#pragma unroll
    for (int n = 0; n < 4; ++n) {
      const int r = wn * 64 + n * 16 + l15;
      const int off = r * 32 + (g ^ ((r >> 1) & 3)) * 8;
      bH4[n] = *reinterpret_cast<const bf16x8*>(L + 8192 + off);
      bL4[n] = *reinterpret_cast<const bf16x8*>(L + 16384 + off);
    }
#pragma unroll
    for (int m = 0; m < 8; ++m)
#pragma unroll
      for (int n = 0; n < 4; ++n) {
        acc[m][n] = __builtin_amdgcn_mfma_f32_16x16x32_bf16(a4[m], bH4[n], acc[m][n], 0, 0, 0);
        acc[m][n] = __builtin_amdgcn_mfma_f32_16x16x32_bf16(a4[m], bL4[n], acc[m][n], 0, 0, 0);
      }
    __syncthreads();
    cur ^= 1;
  }
#undef GEMM_STAGE

  const int yrow0 = t0 + wm * 128;
#pragma unroll
  for (int n = 0; n < 4; ++n) {
    const int colg = o0 + wn * 64 + n * 16 + l15;
    const float bv = bias[colg];
#pragma unroll
    for (int m = 0; m < 8; ++m) {
      const int rbase = yrow0 + m * 16 + g * 4;
#pragma unroll
      for (int r = 0; r < 4; ++r)
        out[(size_t)(rbase + r) * 1024 + colg] = acc[m][n][r] + bv;
    }
  }
}

}  // namespace

extern "C" void kernel_launch(void* const* d_in, const int* in_sizes, int n_in,
                              void* d_out, int out_size, void* d_ws, size_t ws_size,
                              hipStream_t stream) {
  const float* x = (const float*)d_in[0];
  const float* w_approx = (const float*)d_in[1];
  const float* b_approx = (const float*)d_in[2];
  const float* w_detail = (const float*)d_in[3];
  const float* b_detail = (const float*)d_in[4];
  const float* w_out = (const float*)d_in[5];
  const float* b_out = (const float*)d_in[6];
  float* out = (float*)d_out;

  char* ws = (char*)d_ws;
  // merged A plane: 16 batches x 1026 rows x 1024 ushorts = 33,619,968 B
  unsigned short* A = (unsigned short*)(ws);
  unsigned short* pout = (unsigned short*)(ws + 33619968);   // 16x1024x1024 bf16 = 33,554,432 B
  unsigned short* rc = (unsigned short*)(ws + 67174400);     // 16384x1024 ushorts = 33,554,432 B
  unsigned short* wtAh = (unsigned short*)(ws + 134348800);  // 6,291,456 B each
  unsigned short* wtAl = (unsigned short*)(ws + 140640256);
  unsigned short* wtDh = (unsigned short*)(ws + 146931712);
  unsigned short* wtDl = (unsigned short*)(ws + 153223168);
  unsigned short* woH = (unsigned short*)(ws + 159514624);   // 2,097,152 B each
  unsigned short* woL = (unsigned short*)(ws + 161611776);

  prep_conv_w<<<2048, 256, 0, stream>>>(w_approx, w_detail, wtAh, wtAl, wtDh, wtDl);
  prep_wout<<<1024, 256, 0, stream>>>(w_out, woH, woL);
  dwt_kernel<<<4096, 256, 0, stream>>>(x, A);

  conv_mm_kernel<<<512, 512, 0, stream>>>(A, wtAh, wtAl, wtDh, wtDl,
                                          b_approx, b_detail, pout);

  idwt_kernel<<<4096, 256, 0, stream>>>(pout, rc);

  gemm_out_kernel<<<256, 512, 0, stream>>>(rc, woH, woL, b_out, out);
}